// Round 1
// baseline (2935.026 us; speedup 1.0000x reference)
//
#include <hip/hip_runtime.h>

#define Bsz 4
#define Ssz 1024
#define Dsz 1024
#define Hn  16
#define DHn 64
#define Ln  6
#define Fsz 4096
#define SCALE_ 0.1767766952966369f  // 1/sqrt(32)

typedef unsigned long long u64;
typedef __attribute__((ext_vector_type(8))) short bf16x8;
typedef __attribute__((ext_vector_type(4))) float f32x4;

__device__ __forceinline__ unsigned short f2bf(float f) {
  union { float f; unsigned int u; } v; v.f = f;
  unsigned int u = v.u + 0x7fffu + ((v.u >> 16) & 1u);
  return (unsigned short)(u >> 16);
}
__device__ __forceinline__ float bf2f(unsigned short h) {
  union { unsigned int u; float f; } v; v.u = ((unsigned int)h) << 16;
  return v.f;
}
__device__ __forceinline__ void gload_lds16(const void* g, void* lds) {
  __builtin_amdgcn_global_load_lds(
      (const __attribute__((address_space(1))) unsigned int*)g,
      (__attribute__((address_space(3))) unsigned int*)lds, 16, 0, 0);
}

// ---------------- cos/sin tables: [S][32] f32 each ----------------
__global__ __launch_bounds__(256) void k_cossin(float* __restrict__ cosT, float* __restrict__ sinT) {
  int idx = blockIdx.x * 256 + threadIdx.x;
  if (idx >= Ssz * 32) return;
  int s = idx >> 5, i = idx & 31;
  float inv = powf(10000.f, -((float)(2 * i)) / 64.f);
  float f = (float)s * inv;
  cosT[idx] = cosf(f);
  sinT[idx] = sinf(f);
}

// ---------------- embedding gather: h[b*S+s][:] = emb[tok] ----------------
__global__ __launch_bounds__(256) void k_embed(const int* __restrict__ tokens,
                                               const float* __restrict__ emb,
                                               float* __restrict__ h) {
  int rs = blockIdx.x;
  int t = threadIdx.x;
  int tok = tokens[rs];
  *(float4*)&h[(u64)rs * Dsz + t * 4] = *(const float4*)&emb[(u64)tok * Dsz + t * 4];
}

// ---------------- layernorm: 1 row / block ----------------
template <int BF16OUT>
__global__ __launch_bounds__(256) void k_layernorm(const float* __restrict__ x,
                                                   const float* __restrict__ sc,
                                                   const float* __restrict__ bi,
                                                   void* outv) {
  int row = blockIdx.x, t = threadIdx.x;
  const float* xr = x + (u64)row * Dsz;
  float4 v = *(const float4*)&xr[t * 4];
  float sm = v.x + v.y + v.z + v.w;
  float sq = v.x * v.x + v.y * v.y + v.z * v.z + v.w * v.w;
#pragma unroll
  for (int m = 1; m < 64; m <<= 1) { sm += __shfl_xor(sm, m); sq += __shfl_xor(sq, m); }
  __shared__ float r1[4], r2[4];
  if ((t & 63) == 0) { r1[t >> 6] = sm; r2[t >> 6] = sq; }
  __syncthreads();
  sm = r1[0] + r1[1] + r1[2] + r1[3];
  sq = r2[0] + r2[1] + r2[2] + r2[3];
  float mean = sm * (1.f / Dsz);
  float inv = rsqrtf(sq * (1.f / Dsz) - mean * mean + 1e-5f);
  float4 s4 = *(const float4*)&sc[t * 4];
  float4 b4 = *(const float4*)&bi[t * 4];
  float y0 = (v.x - mean) * inv * s4.x + b4.x;
  float y1 = (v.y - mean) * inv * s4.y + b4.y;
  float y2 = (v.z - mean) * inv * s4.z + b4.z;
  float y3 = (v.w - mean) * inv * s4.w + b4.w;
  if (BF16OUT) {
    ushort4 o; o.x = f2bf(y0); o.y = f2bf(y1); o.z = f2bf(y2); o.w = f2bf(y3);
    *(ushort4*)((unsigned short*)outv + (u64)row * Dsz + t * 4) = o;
  } else {
    float4 o; o.x = y0; o.y = y1; o.z = y2; o.w = y3;
    *(float4*)((float*)outv + (u64)row * Dsz + t * 4) = o;
  }
}

// ---------------- weight convert+transpose: f32 [K][N] -> bf16 [N][K] ----------------
__global__ __launch_bounds__(256) void k_wt(const float* __restrict__ in,
                                            unsigned short* __restrict__ out, int K, int N) {
  __shared__ float tile[32][33];
  int nb = blockIdx.x * 32, kb = blockIdx.y * 32;
  int t = threadIdx.x;
  int r = t >> 3, c4 = (t & 7) * 4;
  float4 v = *(const float4*)&in[(u64)(kb + r) * N + nb + c4];
  tile[r][c4] = v.x; tile[r][c4 + 1] = v.y; tile[r][c4 + 2] = v.z; tile[r][c4 + 3] = v.w;
  __syncthreads();
  ushort4 o;
  o.x = f2bf(tile[c4][r]); o.y = f2bf(tile[c4 + 1][r]);
  o.z = f2bf(tile[c4 + 2][r]); o.w = f2bf(tile[c4 + 3][r]);
  *(ushort4*)&out[(u64)(nb + r) * K + kb + c4] = o;
}

// ---------------- GEMM: C[M,N] = A[M,K](bf16) @ Bt[N,K](bf16)^T ----------------
// EPI 0: store f32; EPI 1: store bf16; EPI 2: Cout_f32 = resid + C
template <int EPI>
__global__ __launch_bounds__(256) void k_gemm(const unsigned short* __restrict__ A,
                                              const unsigned short* __restrict__ Bt,
                                              const float* resid, void* Cout,
                                              int M, int N, int K) {
  __shared__ unsigned short As[128 * 32] __attribute__((aligned(16)));
  __shared__ unsigned short Bs[128 * 32] __attribute__((aligned(16)));
  int t = threadIdx.x, w = t >> 6, l = t & 63;
  int bx = blockIdx.x, by = blockIdx.y;
  int wr = (w >> 1) * 64, wc = (w & 1) * 64;
  int lr = l & 15, lq = l >> 4;
  f32x4 acc[4][4];
#pragma unroll
  for (int i = 0; i < 4; ++i)
#pragma unroll
    for (int j = 0; j < 4; ++j) acc[i][j] = (f32x4){0.f, 0.f, 0.f, 0.f};
  const char* Ab = (const char*)(A + (u64)(by * 128) * K);
  const char* Bb = (const char*)(Bt + (u64)(bx * 128) * K);
  int s0 = t, s1 = t + 256;
  int r0 = s0 >> 2, c0 = s0 & 3, r1 = s1 >> 2, c1 = s1 & 3;
  u64 K2 = (u64)K * 2;
  for (int kt = 0; kt < K; kt += 32) {
    __syncthreads();
    gload_lds16(Ab + (u64)r0 * K2 + (u64)kt * 2 + c0 * 16, (char*)As + s0 * 16);
    gload_lds16(Ab + (u64)r1 * K2 + (u64)kt * 2 + c1 * 16, (char*)As + s1 * 16);
    gload_lds16(Bb + (u64)r0 * K2 + (u64)kt * 2 + c0 * 16, (char*)Bs + s0 * 16);
    gload_lds16(Bb + (u64)r1 * K2 + (u64)kt * 2 + c1 * 16, (char*)Bs + s1 * 16);
    __syncthreads();
    bf16x8 af[4], bfr[4];
#pragma unroll
    for (int mt = 0; mt < 4; ++mt) af[mt] = *(const bf16x8*)&As[(wr + mt * 16 + lr) * 32 + lq * 8];
#pragma unroll
    for (int nt = 0; nt < 4; ++nt) bfr[nt] = *(const bf16x8*)&Bs[(wc + nt * 16 + lr) * 32 + lq * 8];
#pragma unroll
    for (int mt = 0; mt < 4; ++mt)
#pragma unroll
      for (int nt = 0; nt < 4; ++nt)
        acc[mt][nt] = __builtin_amdgcn_mfma_f32_16x16x32_bf16(af[mt], bfr[nt], acc[mt][nt], 0, 0, 0);
  }
#pragma unroll
  for (int mt = 0; mt < 4; ++mt)
#pragma unroll
    for (int nt = 0; nt < 4; ++nt)
#pragma unroll
      for (int r = 0; r < 4; ++r) {
        int row = by * 128 + wr + mt * 16 + lq * 4 + r;
        int col = bx * 128 + wc + nt * 16 + lr;
        u64 idx = (u64)row * N + col;
        float v = acc[mt][nt][r];
        if (EPI == 0) ((float*)Cout)[idx] = v;
        else if (EPI == 1) ((unsigned short*)Cout)[idx] = f2bf(v);
        else ((float*)Cout)[idx] = resid[idx] + v;
      }
}

// ---------------- RoPE + head split + V transpose ----------------
// qkv bf16 [B,S,3D] -> q_r,k_r bf16 [B,H,S,64] (roped), v_t bf16 [B,H,64,S]
__global__ __launch_bounds__(256) void k_rope_heads(const unsigned short* __restrict__ qkv,
                                                    const float* __restrict__ cosT,
                                                    const float* __restrict__ sinT,
                                                    unsigned short* __restrict__ q_r,
                                                    unsigned short* __restrict__ k_r,
                                                    unsigned short* __restrict__ v_t) {
  int st = blockIdx.x, hh = blockIdx.y, b = blockIdx.z;
  int t = threadIdx.x;
  int r = t >> 2, cg = (t & 3) * 16;
  int s = st * 64 + r;
  u64 rowb = ((u64)(b * Ssz + s)) * (3 * Dsz);
  u64 bh = (u64)(b * Hn + hh);
  const unsigned int* qp = (const unsigned int*)(qkv + rowb + hh * 64 + cg);
  const unsigned int* kp = (const unsigned int*)(qkv + rowb + Dsz + hh * 64 + cg);
  const unsigned short* vp = qkv + rowb + 2 * Dsz + hh * 64 + cg;
  uint4 qv0 = *(const uint4*)qp, qv1 = *(const uint4*)(qp + 4);
  uint4 kv0 = *(const uint4*)kp, kv1 = *(const uint4*)(kp + 4);
  int i0 = s * 32 + (cg >> 1);
  float4 cA0 = *(const float4*)&cosT[i0], cA1 = *(const float4*)&cosT[i0 + 4];
  float4 sA0 = *(const float4*)&sinT[i0], sA1 = *(const float4*)&sinT[i0 + 4];
  unsigned int qw[8] = {qv0.x, qv0.y, qv0.z, qv0.w, qv1.x, qv1.y, qv1.z, qv1.w};
  unsigned int kw[8] = {kv0.x, kv0.y, kv0.z, kv0.w, kv1.x, kv1.y, kv1.z, kv1.w};
  float cA[8] = {cA0.x, cA0.y, cA0.z, cA0.w, cA1.x, cA1.y, cA1.z, cA1.w};
  float sA[8] = {sA0.x, sA0.y, sA0.z, sA0.w, sA1.x, sA1.y, sA1.z, sA1.w};
  unsigned int oq[8], ok[8];
#pragma unroll
  for (int j = 0; j < 8; ++j) {
    float c = cA[j], sn = sA[j];
    float qe = bf2f((unsigned short)(qw[j] & 0xffff)), qo = bf2f((unsigned short)(qw[j] >> 16));
    float ke = bf2f((unsigned short)(kw[j] & 0xffff)), ko = bf2f((unsigned short)(kw[j] >> 16));
    oq[j] = (unsigned int)f2bf(qe * c - qo * sn) | ((unsigned int)f2bf(qo * c + qe * sn) << 16);
    ok[j] = (unsigned int)f2bf(ke * c - ko * sn) | ((unsigned int)f2bf(ko * c + ke * sn) << 16);
  }
  u64 dst = (bh * Ssz + s) * 64 + cg;
  uint4 a0; a0.x = oq[0]; a0.y = oq[1]; a0.z = oq[2]; a0.w = oq[3];
  uint4 a1; a1.x = oq[4]; a1.y = oq[5]; a1.z = oq[6]; a1.w = oq[7];
  ((uint4*)&q_r[dst])[0] = a0; ((uint4*)&q_r[dst])[1] = a1;
  uint4 b0; b0.x = ok[0]; b0.y = ok[1]; b0.z = ok[2]; b0.w = ok[3];
  uint4 b1; b1.x = ok[4]; b1.y = ok[5]; b1.z = ok[6]; b1.w = ok[7];
  ((uint4*)&k_r[dst])[0] = b0; ((uint4*)&k_r[dst])[1] = b1;
  // V transpose through LDS
  __shared__ unsigned short vt_lds[64][65];
  uint4 vv0 = *(const uint4*)vp, vv1 = *(const uint4*)(vp + 8);
  unsigned int vw[8] = {vv0.x, vv0.y, vv0.z, vv0.w, vv1.x, vv1.y, vv1.z, vv1.w};
#pragma unroll
  for (int j = 0; j < 8; ++j) {
    vt_lds[r][cg + 2 * j] = (unsigned short)(vw[j] & 0xffff);
    vt_lds[r][cg + 2 * j + 1] = (unsigned short)(vw[j] >> 16);
  }
  __syncthreads();
  unsigned int ov[8];
#pragma unroll
  for (int j = 0; j < 8; ++j) {
    unsigned short lo = vt_lds[cg + 2 * j][r], hi = vt_lds[cg + 2 * j + 1][r];
    ov[j] = (unsigned int)lo | ((unsigned int)hi << 16);
  }
  u64 vdst = bh * ((u64)DHn * Ssz) + (u64)r * Ssz + st * 64 + cg;
  uint4 c0v; c0v.x = ov[0]; c0v.y = ov[1]; c0v.z = ov[2]; c0v.w = ov[3];
  uint4 c1v; c1v.x = ov[4]; c1v.y = ov[5]; c1v.z = ov[6]; c1v.w = ov[7];
  ((uint4*)&v_t[vdst])[0] = c0v; ((uint4*)&v_t[vdst])[1] = c1v;
}

// ---------------- fused attention ----------------
// logits[q][k] = (k<=q ? q_hi.k_hi : q_lo.k_lo)*scale ; full softmax over k ; O = P @ V
__global__ __launch_bounds__(256) void k_attn(const unsigned short* __restrict__ qr,
                                              const unsigned short* __restrict__ kr,
                                              const unsigned short* __restrict__ vt,
                                              unsigned short* __restrict__ outp) {
  int qt = blockIdx.x, hh = blockIdx.y, b = blockIdx.z;
  int t = threadIdx.x, w = t >> 6, l = t & 63;
  int lr = l & 15, lq = l >> 4;
  u64 bh = (u64)(b * Hn + hh);
  const unsigned short* Qp = qr + bh * (Ssz * DHn);
  const unsigned short* Kp = kr + bh * (Ssz * DHn);
  const unsigned short* Vp = vt + bh * ((u64)DHn * Ssz);
  int q0 = qt * 64 + w * 16;
  bf16x8 qlo = *(const bf16x8*)&Qp[(q0 + lr) * DHn + lq * 8];
  bf16x8 qhi = *(const bf16x8*)&Qp[(q0 + lr) * DHn + 32 + lq * 8];
  float mrun[4], lsum[4];
  f32x4 o[4];
#pragma unroll
  for (int r = 0; r < 4; ++r) { mrun[r] = -1e30f; lsum[r] = 0.f; o[r] = (f32x4){0.f, 0.f, 0.f, 0.f}; }
  __shared__ unsigned short Plds[4][16 * 128] __attribute__((aligned(16)));
  char* Pw = (char*)&Plds[w][0];
  for (int kb = 0; kb < Ssz; kb += 128) {
    float p[8][4];
    float bm[4] = {-1e30f, -1e30f, -1e30f, -1e30f};
#pragma unroll
    for (int ct = 0; ct < 8; ++ct) {
      int kr0 = kb + ct * 16;
      bf16x8 klo = *(const bf16x8*)&Kp[(kr0 + lr) * DHn + lq * 8];
      bf16x8 khi = *(const bf16x8*)&Kp[(kr0 + lr) * DHn + 32 + lq * 8];
      f32x4 z = (f32x4){0.f, 0.f, 0.f, 0.f};
      f32x4 slo = __builtin_amdgcn_mfma_f32_16x16x32_bf16(qlo, klo, z, 0, 0, 0);
      f32x4 shi = __builtin_amdgcn_mfma_f32_16x16x32_bf16(qhi, khi, z, 0, 0, 0);
      int kcol = kr0 + lr;
#pragma unroll
      for (int r = 0; r < 4; ++r) {
        int qrow = q0 + lq * 4 + r;
        float val = (kcol <= qrow ? shi[r] : slo[r]) * SCALE_;
        p[ct][r] = val;
        bm[r] = fmaxf(bm[r], val);
      }
    }
#pragma unroll
    for (int r = 0; r < 4; ++r) {
      float v = bm[r];
      v = fmaxf(v, __shfl_xor(v, 1));
      v = fmaxf(v, __shfl_xor(v, 2));
      v = fmaxf(v, __shfl_xor(v, 4));
      v = fmaxf(v, __shfl_xor(v, 8));
      float mn = fmaxf(mrun[r], v);
      float scf = __expf(mrun[r] - mn);
      mrun[r] = mn;
      lsum[r] *= scf;
      o[0][r] *= scf; o[1][r] *= scf; o[2][r] *= scf; o[3][r] *= scf;
    }
#pragma unroll
    for (int ct = 0; ct < 8; ++ct)
#pragma unroll
      for (int r = 0; r < 4; ++r) {
        float e = __expf(p[ct][r] - mrun[r]);
        lsum[r] += e;
        int prow = lq * 4 + r;
        int byte_ = (prow * 256 + ct * 32 + lr * 2) ^ ((prow & 7) << 4);
        *(unsigned short*)(Pw + byte_) = f2bf(e);
      }
    asm volatile("s_waitcnt lgkmcnt(0)" ::: "memory");
    __builtin_amdgcn_sched_barrier(0);
#pragma unroll
    for (int ks = 0; ks < 4; ++ks) {
      int byte_ = (lr * 256 + ks * 64 + lq * 16) ^ ((lr & 7) << 4);
      bf16x8 pa = *(const bf16x8*)(Pw + byte_);
#pragma unroll
      for (int nt = 0; nt < 4; ++nt) {
        bf16x8 vb = *(const bf16x8*)&Vp[(u64)(nt * 16 + lr) * Ssz + kb + ks * 32 + lq * 8];
        o[nt] = __builtin_amdgcn_mfma_f32_16x16x32_bf16(pa, vb, o[nt], 0, 0, 0);
      }
    }
  }
#pragma unroll
  for (int r = 0; r < 4; ++r) {
    float v = lsum[r];
    v += __shfl_xor(v, 1); v += __shfl_xor(v, 2); v += __shfl_xor(v, 4); v += __shfl_xor(v, 8);
    lsum[r] = v;
  }
  u64 obase = ((u64)b * Ssz) * Dsz + (u64)hh * DHn;
#pragma unroll
  for (int nt = 0; nt < 4; ++nt)
#pragma unroll
    for (int r = 0; r < 4; ++r) {
      int qrow = q0 + lq * 4 + r;
      outp[obase + (u64)qrow * Dsz + nt * 16 + lr] = f2bf(o[nt][r] / lsum[r]);
    }
}

// ---------------- SiLU gate: m = silu(g[:, :F]) * g[:, F:] ----------------
__global__ __launch_bounds__(256) void k_silu(const unsigned short* __restrict__ g,
                                              unsigned short* __restrict__ mo) {
  u64 idx = (u64)blockIdx.x * 256 + threadIdx.x;
  u64 e = idx * 4;
  u64 row = e >> 12, col = e & 4095;
  const unsigned short* ap = &g[row * 8192 + col];
  ushort4 av = *(const ushort4*)ap;
  ushort4 bv = *(const ushort4*)(ap + 4096);
  float a0 = bf2f(av.x), a1 = bf2f(av.y), a2 = bf2f(av.z), a3 = bf2f(av.w);
  float b0 = bf2f(bv.x), b1 = bf2f(bv.y), b2 = bf2f(bv.z), b3 = bf2f(bv.w);
  ushort4 o;
  o.x = f2bf(a0 / (1.f + __expf(-a0)) * b0);
  o.y = f2bf(a1 / (1.f + __expf(-a1)) * b1);
  o.z = f2bf(a2 / (1.f + __expf(-a2)) * b2);
  o.w = f2bf(a3 / (1.f + __expf(-a3)) * b3);
  *(ushort4*)&mo[e] = o;
}

// ---------------- scores = hf @ w_score ----------------
__global__ __launch_bounds__(256) void k_scores(const float* __restrict__ hf,
                                                const float* __restrict__ wsc,
                                                float* __restrict__ scores) {
  int row = blockIdx.x * 4 + (threadIdx.x >> 6);
  int l = threadIdx.x & 63;
  const float* xr = hf + (u64)row * Dsz;
  float acc = 0.f;
#pragma unroll
  for (int j = 0; j < 4; ++j) {
    float4 v = *(const float4*)&xr[(j * 64 + l) * 4];
    float4 ww = *(const float4*)&wsc[(j * 64 + l) * 4];
    acc += v.x * ww.x + v.y * ww.y + v.z * ww.z + v.w * ww.w;
  }
#pragma unroll
  for (int m = 1; m < 64; m <<= 1) acc += __shfl_xor(acc, m);
  if (l == 0) scores[row] = acc;
}

// ---------------- softmax over S (per batch) ----------------
__global__ __launch_bounds__(256) void k_softmax_s(const float* __restrict__ sc,
                                                   float* __restrict__ pw) {
  int b = blockIdx.x, t = threadIdx.x;
  const float* sr = sc + b * Ssz;
  float4 v = *(const float4*)&sr[t * 4];
  float mx = fmaxf(fmaxf(v.x, v.y), fmaxf(v.z, v.w));
#pragma unroll
  for (int m = 1; m < 64; m <<= 1) mx = fmaxf(mx, __shfl_xor(mx, m));
  __shared__ float red[4];
  if ((t & 63) == 0) red[t >> 6] = mx;
  __syncthreads();
  mx = fmaxf(fmaxf(red[0], red[1]), fmaxf(red[2], red[3]));
  float e0 = __expf(v.x - mx), e1 = __expf(v.y - mx), e2 = __expf(v.z - mx), e3 = __expf(v.w - mx);
  float sm = e0 + e1 + e2 + e3;
#pragma unroll
  for (int m = 1; m < 64; m <<= 1) sm += __shfl_xor(sm, m);
  __shared__ float red2[4];
  if ((t & 63) == 0) red2[t >> 6] = sm;
  __syncthreads();
  sm = red2[0] + red2[1] + red2[2] + red2[3];
  float inv = 1.f / sm;
  float4 o; o.x = e0 * inv; o.y = e1 * inv; o.z = e2 * inv; o.w = e3 * inv;
  *(float4*)&pw[b * Ssz + t * 4] = o;
}

// ---------------- pooled[b][d] = sum_s pw[b][s]*hf[b][s][d] ----------------
__global__ __launch_bounds__(256) void k_pool(const float* __restrict__ hf,
                                              const float* __restrict__ pw,
                                              float* __restrict__ pooled) {
  int b = blockIdx.y;
  int d = blockIdx.x * 256 + threadIdx.x;
  const float* pwb = pw + b * Ssz;
  float acc = 0.f;
  for (int s = 0; s < Ssz; ++s) acc += pwb[s] * hf[((u64)(b * Ssz + s)) * Dsz + d];
  pooled[b * Dsz + d] = acc;
}

// ---------------- out[b][n] = sum_k pooled[b][k]*wcls[k][n] ----------------
__global__ __launch_bounds__(256) void k_cls(const float* __restrict__ pooled,
                                             const float* __restrict__ wcls,
                                             float* __restrict__ outp) {
  int n = blockIdx.x * 64 + (threadIdx.x & 63);
  int b = threadIdx.x >> 6;
  const float* pb = pooled + b * Dsz;
  float acc = 0.f;
  for (int k = 0; k < Dsz; ++k) acc += pb[k] * wcls[(u64)k * Ssz + n];
  outp[b * Ssz + n] = acc;
}

extern "C" void kernel_launch(void* const* d_in, const int* in_sizes, int n_in,
                              void* d_out, int out_size, void* d_ws, size_t ws_size,
                              hipStream_t stream) {
  (void)in_sizes; (void)n_in; (void)out_size; (void)ws_size;
  const int*   tokens  = (const int*)  d_in[0];
  const float* tok_emb = (const float*)d_in[1];
  const float* ln1_s   = (const float*)d_in[2];
  const float* ln1_b   = (const float*)d_in[3];
  const float* w_qkv   = (const float*)d_in[4];
  const float* w_proj  = (const float*)d_in[5];
  const float* ln2_s   = (const float*)d_in[6];
  const float* ln2_b   = (const float*)d_in[7];
  const float* w_in    = (const float*)d_in[8];
  const float* w_out   = (const float*)d_in[9];
  const float* lnf_s   = (const float*)d_in[10];
  const float* lnf_b   = (const float*)d_in[11];
  const float* w_score = (const float*)d_in[12];
  const float* w_cls   = (const float*)d_in[13];
  float* outp = (float*)d_out;
  char* ws = (char*)d_ws;

  // workspace layout (~152.3 MiB total); union region reuses qkv/q/k/v/attn_out for g and hf
  unsigned short* qkv    = (unsigned short*)(ws + 0);            // 25165824 B
  unsigned short* q_r    = (unsigned short*)(ws + 25165824ull);  // 8388608 B
  unsigned short* k_r    = (unsigned short*)(ws + 33554432ull);  // 8388608 B
  unsigned short* v_t    = (unsigned short*)(ws + 41943040ull);  // 8388608 B
  unsigned short* a_out  = (unsigned short*)(ws + 50331648ull);  // 8388608 B
  unsigned short* g      = (unsigned short*)(ws + 0);            // 67108864 B (aliases the above, all dead)
  float*          hf     = (float*)(ws + 0);                     // 16777216 B (aliases, end of net)
  unsigned short* x_ln   = (unsigned short*)(ws + 67108864ull);  // 8388608 B
  unsigned short* mbuf   = (unsigned short*)(ws + 75497472ull);  // 33554432 B
  float*          h      = (float*)(ws + 109051904ull);          // 16777216 B
  unsigned short* wqkv_t = (unsigned short*)(ws + 125829120ull); // 6291456 B
  unsigned short* wproj_t= (unsigned short*)(ws + 132120576ull); // 2097152 B
  unsigned short* win_t  = (unsigned short*)(ws + 134217728ull); // 16777216 B
  unsigned short* wout_t = (unsigned short*)(ws + 150994944ull); // 8388608 B
  float* cosT    = (float*)(ws + 159383552ull);                  // 131072 B
  float* sinT    = (float*)(ws + 159514624ull);                  // 131072 B
  float* scoresb = (float*)(ws + 159645696ull);                  // 16384 B
  float* pwb     = (float*)(ws + 159662080ull);                  // 16384 B
  float* pooledb = (float*)(ws + 159678464ull);                  // 16384 B

  dim3 blk(256);
  k_cossin<<<dim3(128), blk, 0, stream>>>(cosT, sinT);
  k_embed<<<dim3(4096), blk, 0, stream>>>(tokens, tok_emb, h);

  for (int l = 0; l < Ln; ++l) {
    k_layernorm<1><<<dim3(4096), blk, 0, stream>>>(h, ln1_s + l * Dsz, ln1_b + l * Dsz, (void*)x_ln);
    k_wt<<<dim3(96, 32), blk, 0, stream>>>(w_qkv + (u64)l * Dsz * 3 * Dsz, wqkv_t, Dsz, 3 * Dsz);
    k_gemm<1><<<dim3(24, 32), blk, 0, stream>>>(x_ln, wqkv_t, nullptr, (void*)qkv, 4096, 3072, 1024);
    k_rope_heads<<<dim3(16, 16, 4), blk, 0, stream>>>(qkv, cosT, sinT, q_r, k_r, v_t);
    k_attn<<<dim3(16, 16, 4), blk, 0, stream>>>(q_r, k_r, v_t, a_out);
    k_wt<<<dim3(32, 32), blk, 0, stream>>>(w_proj + (u64)l * Dsz * Dsz, wproj_t, Dsz, Dsz);
    k_gemm<2><<<dim3(8, 32), blk, 0, stream>>>(a_out, wproj_t, h, (void*)h, 4096, 1024, 1024);
    k_layernorm<1><<<dim3(4096), blk, 0, stream>>>(h, ln2_s + l * Dsz, ln2_b + l * Dsz, (void*)x_ln);
    k_wt<<<dim3(256, 32), blk, 0, stream>>>(w_in + (u64)l * Dsz * 2 * Fsz, win_t, Dsz, 2 * Fsz);
    k_gemm<1><<<dim3(64, 32), blk, 0, stream>>>(x_ln, win_t, nullptr, (void*)g, 4096, 8192, 1024);
    k_silu<<<dim3(16384), blk, 0, stream>>>(g, mbuf);
    k_wt<<<dim3(32, 128), blk, 0, stream>>>(w_out + (u64)l * Fsz * Dsz, wout_t, Fsz, Dsz);
    k_gemm<2><<<dim3(8, 32), blk, 0, stream>>>(mbuf, wout_t, h, (void*)h, 4096, 1024, 4096);
  }

  k_layernorm<0><<<dim3(4096), blk, 0, stream>>>(h, lnf_s, lnf_b, (void*)hf);
  k_scores<<<dim3(1024), blk, 0, stream>>>(hf, w_score, scoresb);
  k_softmax_s<<<dim3(4), blk, 0, stream>>>(scoresb, pwb);
  k_pool<<<dim3(4, 4), blk, 0, stream>>>(hf, pwb, pooledb);
  k_cls<<<dim3(16), blk, 0, stream>>>(pooledb, w_cls, outp);
}

// Round 2
// 2339.164 us; speedup vs baseline: 1.2547x; 1.2547x over previous
//
#include <hip/hip_runtime.h>

#define Bsz 4
#define Ssz 1024
#define Dsz 1024
#define Hn  16
#define DHn 64
#define Ln  6
#define Fsz 4096
#define SCALE_ 0.1767766952966369f  // 1/sqrt(32)

typedef unsigned long long u64;
typedef __attribute__((ext_vector_type(8))) short bf16x8;
typedef __attribute__((ext_vector_type(4))) float f32x4;

__device__ __forceinline__ unsigned short f2bf(float f) {
  union { float f; unsigned int u; } v; v.f = f;
  unsigned int u = v.u + 0x7fffu + ((v.u >> 16) & 1u);
  return (unsigned short)(u >> 16);
}
__device__ __forceinline__ float bf2f(unsigned short h) {
  union { unsigned int u; float f; } v; v.u = ((unsigned int)h) << 16;
  return v.f;
}
__device__ __forceinline__ void gload_lds16(const void* g, void* lds) {
  __builtin_amdgcn_global_load_lds(
      (const __attribute__((address_space(1))) unsigned int*)g,
      (__attribute__((address_space(3))) unsigned int*)lds, 16, 0, 0);
}

// ---------------- cos/sin tables: [S][32] f32 each ----------------
__global__ __launch_bounds__(256) void k_cossin(float* __restrict__ cosT, float* __restrict__ sinT) {
  int idx = blockIdx.x * 256 + threadIdx.x;
  if (idx >= Ssz * 32) return;
  int s = idx >> 5, i = idx & 31;
  float inv = powf(10000.f, -((float)(2 * i)) / 64.f);
  float f = (float)s * inv;
  cosT[idx] = cosf(f);
  sinT[idx] = sinf(f);
}

// ---------------- embedding gather ----------------
__global__ __launch_bounds__(256) void k_embed(const int* __restrict__ tokens,
                                               const float* __restrict__ emb,
                                               float* __restrict__ h) {
  int rs = blockIdx.x;
  int t = threadIdx.x;
  int tok = tokens[rs];
  *(float4*)&h[(u64)rs * Dsz + t * 4] = *(const float4*)&emb[(u64)tok * Dsz + t * 4];
}

// ---------------- layernorm: 1 row / block ----------------
template <int BF16OUT>
__global__ __launch_bounds__(256) void k_layernorm(const float* __restrict__ x,
                                                   const float* __restrict__ sc,
                                                   const float* __restrict__ bi,
                                                   void* outv) {
  int row = blockIdx.x, t = threadIdx.x;
  const float* xr = x + (u64)row * Dsz;
  float4 v = *(const float4*)&xr[t * 4];
  float sm = v.x + v.y + v.z + v.w;
  float sq = v.x * v.x + v.y * v.y + v.z * v.z + v.w * v.w;
#pragma unroll
  for (int m = 1; m < 64; m <<= 1) { sm += __shfl_xor(sm, m); sq += __shfl_xor(sq, m); }
  __shared__ float r1[4], r2[4];
  if ((t & 63) == 0) { r1[t >> 6] = sm; r2[t >> 6] = sq; }
  __syncthreads();
  sm = r1[0] + r1[1] + r1[2] + r1[3];
  sq = r2[0] + r2[1] + r2[2] + r2[3];
  float mean = sm * (1.f / Dsz);
  float inv = rsqrtf(sq * (1.f / Dsz) - mean * mean + 1e-5f);
  float4 s4 = *(const float4*)&sc[t * 4];
  float4 b4 = *(const float4*)&bi[t * 4];
  float y0 = (v.x - mean) * inv * s4.x + b4.x;
  float y1 = (v.y - mean) * inv * s4.y + b4.y;
  float y2 = (v.z - mean) * inv * s4.z + b4.z;
  float y3 = (v.w - mean) * inv * s4.w + b4.w;
  if (BF16OUT) {
    ushort4 o; o.x = f2bf(y0); o.y = f2bf(y1); o.z = f2bf(y2); o.w = f2bf(y3);
    *(ushort4*)((unsigned short*)outv + (u64)row * Dsz + t * 4) = o;
  } else {
    float4 o; o.x = y0; o.y = y1; o.z = y2; o.w = y3;
    *(float4*)((float*)outv + (u64)row * Dsz + t * 4) = o;
  }
}

// ---------------- weight convert+transpose: f32 [K][N] -> bf16 [N][K] ----------------
__global__ __launch_bounds__(256) void k_wt(const float* __restrict__ in,
                                            unsigned short* __restrict__ out, int K, int N) {
  __shared__ float tile[32][33];
  int nb = blockIdx.x * 32, kb = blockIdx.y * 32;
  int t = threadIdx.x;
  int r = t >> 3, c4 = (t & 7) * 4;
  float4 v = *(const float4*)&in[(u64)(kb + r) * N + nb + c4];
  tile[r][c4] = v.x; tile[r][c4 + 1] = v.y; tile[r][c4 + 2] = v.z; tile[r][c4 + 3] = v.w;
  __syncthreads();
  ushort4 o;
  o.x = f2bf(tile[c4][r]); o.y = f2bf(tile[c4 + 1][r]);
  o.z = f2bf(tile[c4 + 2][r]); o.w = f2bf(tile[c4 + 3][r]);
  *(ushort4*)&out[(u64)(nb + r) * K + kb + c4] = o;
}

// ---- w_in transpose with a/b column interleave: out[n][k] = in[k][(n>>1)+(n&1)*F] ----
__global__ __launch_bounds__(256) void k_wt_pair(const float* __restrict__ in,
                                                 unsigned short* __restrict__ out) {
  __shared__ float tile[32][33];
  int nb = blockIdx.x * 32, kb = blockIdx.y * 32;
  int t = threadIdx.x;
  int r = t >> 3, c4 = (t & 7) * 4;
  int s0 = nb >> 1;
  int srccol = (c4 < 16) ? (s0 + c4) : (Fsz + s0 + (c4 - 16));
  float4 v = *(const float4*)&in[(u64)(kb + r) * (2 * Fsz) + srccol];
  tile[r][c4] = v.x; tile[r][c4 + 1] = v.y; tile[r][c4 + 2] = v.z; tile[r][c4 + 3] = v.w;
  __syncthreads();
  int sc = (r >> 1) + (r & 1) * 16;
  ushort4 o;
  o.x = f2bf(tile[c4][sc]); o.y = f2bf(tile[c4 + 1][sc]);
  o.z = f2bf(tile[c4 + 2][sc]); o.w = f2bf(tile[c4 + 3][sc]);
  *(ushort4*)&out[(u64)(nb + r) * Dsz + kb + c4] = o;
}

// ---------------- GEMM: C[M,N] = A[M,K](bf16) @ Bt[N,K](bf16)^T ----------------
// EPI 0: store f32; EPI 1: store bf16; EPI 2: Cout_f32 = resid + C;
// EPI 3: paired silu-gate: even col = a, odd col = b -> store silu(a)*b bf16 at col/2
template <int EPI>
__global__ __launch_bounds__(256) void k_gemm(const unsigned short* __restrict__ A,
                                              const unsigned short* __restrict__ Bt,
                                              const float* resid, void* Cout,
                                              int M, int N, int K) {
  __shared__ unsigned short As[128 * 32] __attribute__((aligned(16)));
  __shared__ unsigned short Bs[128 * 32] __attribute__((aligned(16)));
  int t = threadIdx.x, w = t >> 6, l = t & 63;
  int bx = blockIdx.x, by = blockIdx.y;
  int wr = (w >> 1) * 64, wc = (w & 1) * 64;
  int lr = l & 15, lq = l >> 4;
  f32x4 acc[4][4];
#pragma unroll
  for (int i = 0; i < 4; ++i)
#pragma unroll
    for (int j = 0; j < 4; ++j) acc[i][j] = (f32x4){0.f, 0.f, 0.f, 0.f};
  const char* Ab = (const char*)(A + (u64)(by * 128) * K);
  const char* Bb = (const char*)(Bt + (u64)(bx * 128) * K);
  int s0 = t, s1 = t + 256;
  int r0 = s0 >> 2, c0 = s0 & 3, r1 = s1 >> 2, c1 = s1 & 3;
  u64 K2 = (u64)K * 2;
  for (int kt = 0; kt < K; kt += 32) {
    __syncthreads();
    gload_lds16(Ab + (u64)r0 * K2 + (u64)kt * 2 + c0 * 16, (char*)As + s0 * 16);
    gload_lds16(Ab + (u64)r1 * K2 + (u64)kt * 2 + c1 * 16, (char*)As + s1 * 16);
    gload_lds16(Bb + (u64)r0 * K2 + (u64)kt * 2 + c0 * 16, (char*)Bs + s0 * 16);
    gload_lds16(Bb + (u64)r1 * K2 + (u64)kt * 2 + c1 * 16, (char*)Bs + s1 * 16);
    __syncthreads();
    bf16x8 af[4], bfr[4];
#pragma unroll
    for (int mt = 0; mt < 4; ++mt) af[mt] = *(const bf16x8*)&As[(wr + mt * 16 + lr) * 32 + lq * 8];
#pragma unroll
    for (int nt = 0; nt < 4; ++nt) bfr[nt] = *(const bf16x8*)&Bs[(wc + nt * 16 + lr) * 32 + lq * 8];
#pragma unroll
    for (int mt = 0; mt < 4; ++mt)
#pragma unroll
      for (int nt = 0; nt < 4; ++nt)
        acc[mt][nt] = __builtin_amdgcn_mfma_f32_16x16x32_bf16(af[mt], bfr[nt], acc[mt][nt], 0, 0, 0);
  }
#pragma unroll
  for (int mt = 0; mt < 4; ++mt)
#pragma unroll
    for (int nt = 0; nt < 4; ++nt)
#pragma unroll
      for (int r = 0; r < 4; ++r) {
        int row = by * 128 + wr + mt * 16 + lq * 4 + r;
        int col = bx * 128 + wc + nt * 16 + lr;
        float v = acc[mt][nt][r];
        if (EPI == 3) {
          float pv = __shfl_xor(v, 1);
          if ((lr & 1) == 0) {
            float res = v / (1.f + __expf(-v)) * pv;
            ((unsigned short*)Cout)[(u64)row * (N >> 1) + (col >> 1)] = f2bf(res);
          }
        } else {
          u64 idx = (u64)row * N + col;
          if (EPI == 0) ((float*)Cout)[idx] = v;
          else if (EPI == 1) ((unsigned short*)Cout)[idx] = f2bf(v);
          else ((float*)Cout)[idx] = resid[idx] + v;
        }
      }
}

// ---------------- RoPE + head split + V transpose ----------------
__global__ __launch_bounds__(256) void k_rope_heads(const unsigned short* __restrict__ qkv,
                                                    const float* __restrict__ cosT,
                                                    const float* __restrict__ sinT,
                                                    unsigned short* __restrict__ q_r,
                                                    unsigned short* __restrict__ k_r,
                                                    unsigned short* __restrict__ v_t) {
  int st = blockIdx.x, hh = blockIdx.y, b = blockIdx.z;
  int t = threadIdx.x;
  int r = t >> 2, cg = (t & 3) * 16;
  int s = st * 64 + r;
  u64 rowb = ((u64)(b * Ssz + s)) * (3 * Dsz);
  u64 bh = (u64)(b * Hn + hh);
  const unsigned int* qp = (const unsigned int*)(qkv + rowb + hh * 64 + cg);
  const unsigned int* kp = (const unsigned int*)(qkv + rowb + Dsz + hh * 64 + cg);
  const unsigned short* vp = qkv + rowb + 2 * Dsz + hh * 64 + cg;
  uint4 qv0 = *(const uint4*)qp, qv1 = *(const uint4*)(qp + 4);
  uint4 kv0 = *(const uint4*)kp, kv1 = *(const uint4*)(kp + 4);
  int i0 = s * 32 + (cg >> 1);
  float4 cA0 = *(const float4*)&cosT[i0], cA1 = *(const float4*)&cosT[i0 + 4];
  float4 sA0 = *(const float4*)&sinT[i0], sA1 = *(const float4*)&sinT[i0 + 4];
  unsigned int qw[8] = {qv0.x, qv0.y, qv0.z, qv0.w, qv1.x, qv1.y, qv1.z, qv1.w};
  unsigned int kw[8] = {kv0.x, kv0.y, kv0.z, kv0.w, kv1.x, kv1.y, kv1.z, kv1.w};
  float cA[8] = {cA0.x, cA0.y, cA0.z, cA0.w, cA1.x, cA1.y, cA1.z, cA1.w};
  float sA[8] = {sA0.x, sA0.y, sA0.z, sA0.w, sA1.x, sA1.y, sA1.z, sA1.w};
  unsigned int oq[8], ok[8];
#pragma unroll
  for (int j = 0; j < 8; ++j) {
    float c = cA[j], sn = sA[j];
    float qe = bf2f((unsigned short)(qw[j] & 0xffff)), qo = bf2f((unsigned short)(qw[j] >> 16));
    float ke = bf2f((unsigned short)(kw[j] & 0xffff)), ko = bf2f((unsigned short)(kw[j] >> 16));
    oq[j] = (unsigned int)f2bf(qe * c - qo * sn) | ((unsigned int)f2bf(qo * c + qe * sn) << 16);
    ok[j] = (unsigned int)f2bf(ke * c - ko * sn) | ((unsigned int)f2bf(ko * c + ke * sn) << 16);
  }
  u64 dst = (bh * Ssz + s) * 64 + cg;
  uint4 a0; a0.x = oq[0]; a0.y = oq[1]; a0.z = oq[2]; a0.w = oq[3];
  uint4 a1; a1.x = oq[4]; a1.y = oq[5]; a1.z = oq[6]; a1.w = oq[7];
  ((uint4*)&q_r[dst])[0] = a0; ((uint4*)&q_r[dst])[1] = a1;
  uint4 b0; b0.x = ok[0]; b0.y = ok[1]; b0.z = ok[2]; b0.w = ok[3];
  uint4 b1; b1.x = ok[4]; b1.y = ok[5]; b1.z = ok[6]; b1.w = ok[7];
  ((uint4*)&k_r[dst])[0] = b0; ((uint4*)&k_r[dst])[1] = b1;
  __shared__ unsigned short vt_lds[64][65];
  uint4 vv0 = *(const uint4*)vp, vv1 = *(const uint4*)(vp + 8);
  unsigned int vw[8] = {vv0.x, vv0.y, vv0.z, vv0.w, vv1.x, vv1.y, vv1.z, vv1.w};
#pragma unroll
  for (int j = 0; j < 8; ++j) {
    vt_lds[r][cg + 2 * j] = (unsigned short)(vw[j] & 0xffff);
    vt_lds[r][cg + 2 * j + 1] = (unsigned short)(vw[j] >> 16);
  }
  __syncthreads();
  unsigned int ov[8];
#pragma unroll
  for (int j = 0; j < 8; ++j) {
    unsigned short lo = vt_lds[cg + 2 * j][r], hi = vt_lds[cg + 2 * j + 1][r];
    ov[j] = (unsigned int)lo | ((unsigned int)hi << 16);
  }
  u64 vdst = bh * ((u64)DHn * Ssz) + (u64)r * Ssz + st * 64 + cg;
  uint4 c0v; c0v.x = ov[0]; c0v.y = ov[1]; c0v.z = ov[2]; c0v.w = ov[3];
  uint4 c1v; c1v.x = ov[4]; c1v.y = ov[5]; c1v.z = ov[6]; c1v.w = ov[7];
  ((uint4*)&v_t[vdst])[0] = c0v; ((uint4*)&v_t[vdst])[1] = c1v;
}

// ---------------- fused attention (LDS-staged K/V, swapped QK^T) ----------------
// logits[q][k] = (k<=q ? q_hi.k_hi : q_lo.k_lo)*scale ; full softmax over k ; O = P @ V
__global__ __launch_bounds__(256) void k_attn(const unsigned short* __restrict__ qr,
                                              const unsigned short* __restrict__ kr,
                                              const unsigned short* __restrict__ vt,
                                              unsigned short* __restrict__ outp) {
  __shared__ unsigned short Klds[2][2][64 * 32] __attribute__((aligned(16)));
  __shared__ unsigned short Vlds[2][2][64 * 32] __attribute__((aligned(16)));
  __shared__ unsigned short Plds[4][16 * 64] __attribute__((aligned(16)));
  int qt = blockIdx.x, hh = blockIdx.y, b = blockIdx.z;
  int t = threadIdx.x, w = t >> 6, l = t & 63;
  int lr = l & 15, lq = l >> 4;
  u64 bh = (u64)(b * Hn + hh);
  const unsigned short* Qp = qr + bh * (Ssz * DHn);
  const unsigned short* Kp = kr + bh * (Ssz * DHn);
  const unsigned short* Vp = vt + bh * ((u64)DHn * Ssz);
  int q0 = qt * 64 + w * 16;
  bf16x8 qlo = *(const bf16x8*)&Qp[(q0 + lr) * DHn + lq * 8];
  bf16x8 qhi = *(const bf16x8*)&Qp[(q0 + lr) * DHn + 32 + lq * 8];
  int srow = t >> 2;           // 0..63
  int scol8 = (t & 3) * 8;     // 0,8,16,24 (elements)
#define STAGEKV(bufi, kbase)                                                         \
  do {                                                                               \
    gload_lds16(&Kp[((kbase) + srow) * 64 + scol8],      (char*)&Klds[bufi][0][0] + t * 16); \
    gload_lds16(&Kp[((kbase) + srow) * 64 + 32 + scol8], (char*)&Klds[bufi][1][0] + t * 16); \
    gload_lds16(&Vp[(u64)srow * Ssz + (kbase) + scol8],      (char*)&Vlds[bufi][0][0] + t * 16); \
    gload_lds16(&Vp[(u64)srow * Ssz + (kbase) + 32 + scol8], (char*)&Vlds[bufi][1][0] + t * 16); \
  } while (0)
  float m_col = -1e30f, lsum = 0.f;
  float m_row[4] = {-1e30f, -1e30f, -1e30f, -1e30f};
  f32x4 o[4];
#pragma unroll
  for (int r = 0; r < 4; ++r) o[r] = (f32x4){0.f, 0.f, 0.f, 0.f};
  char* Pw = (char*)&Plds[w][0];

  STAGEKV(0, 0);
  asm volatile("s_waitcnt vmcnt(0)" ::: "memory");
  __syncthreads();
  int buf = 0;
  for (int kb = 0; kb < Ssz; kb += 64) {
    if (kb + 64 < Ssz) STAGEKV(buf ^ 1, kb + 64);
    // --- QK^T (swapped: row=k, col=q) ---
    float p[4][4];
#pragma unroll
    for (int ct = 0; ct < 4; ++ct) {
      bf16x8 klo = *(const bf16x8*)&Klds[buf][0][(ct * 16 + lr) * 32 + lq * 8];
      bf16x8 khi = *(const bf16x8*)&Klds[buf][1][(ct * 16 + lr) * 32 + lq * 8];
      f32x4 z = (f32x4){0.f, 0.f, 0.f, 0.f};
      f32x4 slo = __builtin_amdgcn_mfma_f32_16x16x32_bf16(klo, qlo, z, 0, 0, 0);
      f32x4 shi = __builtin_amdgcn_mfma_f32_16x16x32_bf16(khi, qhi, z, 0, 0, 0);
      int kg0 = kb + ct * 16 + lq * 4;
      int qg = q0 + lr;
#pragma unroll
      for (int r = 0; r < 4; ++r) p[ct][r] = (kg0 + r <= qg ? shi[r] : slo[r]) * SCALE_;
    }
    // --- per-lane tile max, reduce across lq groups (2 shuffles) ---
    float tm = p[0][0];
#pragma unroll
    for (int ct = 0; ct < 4; ++ct)
#pragma unroll
      for (int r = 0; r < 4; ++r) tm = fmaxf(tm, p[ct][r]);
    tm = fmaxf(tm, __shfl_xor(tm, 16));
    tm = fmaxf(tm, __shfl_xor(tm, 32));
    float m_new = fmaxf(m_col, tm);
    lsum *= __expf(m_col - m_new);
    m_col = m_new;
    // --- broadcast row max to o-rows, rescale o ---
#pragma unroll
    for (int r = 0; r < 4; ++r) {
      float mr = __shfl(m_col, lq * 4 + r);
      float scf = __expf(m_row[r] - mr);
      m_row[r] = mr;
      o[0][r] *= scf; o[1][r] *= scf; o[2][r] *= scf; o[3][r] *= scf;
    }
    // --- exp + packed P^T write (8B per ct) ---
#pragma unroll
    for (int ct = 0; ct < 4; ++ct) {
      float e0 = __expf(p[ct][0] - m_col);
      float e1 = __expf(p[ct][1] - m_col);
      float e2 = __expf(p[ct][2] - m_col);
      float e3 = __expf(p[ct][3] - m_col);
      lsum += e0 + e1 + e2 + e3;
      ushort4 pk; pk.x = f2bf(e0); pk.y = f2bf(e1); pk.z = f2bf(e2); pk.w = f2bf(e3);
      int byte_ = (lr * 128 + ct * 32 + lq * 8) ^ ((lr & 7) << 4);
      *(ushort4*)(Pw + byte_) = pk;
    }
    asm volatile("s_waitcnt lgkmcnt(0)" ::: "memory");
    __builtin_amdgcn_sched_barrier(0);
    // --- PV ---
#pragma unroll
    for (int ks = 0; ks < 2; ++ks) {
      int pb = (lr * 128 + ks * 64 + lq * 16) ^ ((lr & 7) << 4);
      bf16x8 pa = *(const bf16x8*)(Pw + pb);
#pragma unroll
      for (int nt = 0; nt < 4; ++nt) {
        bf16x8 vb = *(const bf16x8*)&Vlds[buf][ks][(nt * 16 + lr) * 32 + lq * 8];
        o[nt] = __builtin_amdgcn_mfma_f32_16x16x32_bf16(pa, vb, o[nt], 0, 0, 0);
      }
    }
    asm volatile("s_waitcnt vmcnt(0)" ::: "memory");
    __syncthreads();
    buf ^= 1;
  }
  lsum += __shfl_xor(lsum, 16);
  lsum += __shfl_xor(lsum, 32);
  u64 obase = ((u64)b * Ssz) * Dsz + (u64)hh * DHn;
#pragma unroll
  for (int r = 0; r < 4; ++r) {
    float ls = __shfl(lsum, lq * 4 + r);
    float inv = 1.f / ls;
    int qrow = q0 + lq * 4 + r;
#pragma unroll
    for (int nt = 0; nt < 4; ++nt)
      outp[obase + (u64)qrow * Dsz + nt * 16 + lr] = f2bf(o[nt][r] * inv);
  }
#undef STAGEKV
}

// ---------------- scores = hf @ w_score ----------------
__global__ __launch_bounds__(256) void k_scores(const float* __restrict__ hf,
                                                const float* __restrict__ wsc,
                                                float* __restrict__ scores) {
  int row = blockIdx.x * 4 + (threadIdx.x >> 6);
  int l = threadIdx.x & 63;
  const float* xr = hf + (u64)row * Dsz;
  float acc = 0.f;
#pragma unroll
  for (int j = 0; j < 4; ++j) {
    float4 v = *(const float4*)&xr[(j * 64 + l) * 4];
    float4 ww = *(const float4*)&wsc[(j * 64 + l) * 4];
    acc += v.x * ww.x + v.y * ww.y + v.z * ww.z + v.w * ww.w;
  }
#pragma unroll
  for (int m = 1; m < 64; m <<= 1) acc += __shfl_xor(acc, m);
  if (l == 0) scores[row] = acc;
}

// ---------------- softmax over S (per batch) ----------------
__global__ __launch_bounds__(256) void k_softmax_s(const float* __restrict__ sc,
                                                   float* __restrict__ pw) {
  int b = blockIdx.x, t = threadIdx.x;
  const float* sr = sc + b * Ssz;
  float4 v = *(const float4*)&sr[t * 4];
  float mx = fmaxf(fmaxf(v.x, v.y), fmaxf(v.z, v.w));
#pragma unroll
  for (int m = 1; m < 64; m <<= 1) mx = fmaxf(mx, __shfl_xor(mx, m));
  __shared__ float red[4];
  if ((t & 63) == 0) red[t >> 6] = mx;
  __syncthreads();
  mx = fmaxf(fmaxf(red[0], red[1]), fmaxf(red[2], red[3]));
  float e0 = __expf(v.x - mx), e1 = __expf(v.y - mx), e2 = __expf(v.z - mx), e3 = __expf(v.w - mx);
  float sm = e0 + e1 + e2 + e3;
#pragma unroll
  for (int m = 1; m < 64; m <<= 1) sm += __shfl_xor(sm, m);
  __shared__ float red2[4];
  if ((t & 63) == 0) red2[t >> 6] = sm;
  __syncthreads();
  sm = red2[0] + red2[1] + red2[2] + red2[3];
  float inv = 1.f / sm;
  float4 o; o.x = e0 * inv; o.y = e1 * inv; o.z = e2 * inv; o.w = e3 * inv;
  *(float4*)&pw[b * Ssz + t * 4] = o;
}

// ---------------- pooled[b][d] = sum_s pw[b][s]*hf[b][s][d] ----------------
__global__ __launch_bounds__(256) void k_pool(const float* __restrict__ hf,
                                              const float* __restrict__ pw,
                                              float* __restrict__ pooled) {
  int b = blockIdx.y;
  int d = blockIdx.x * 256 + threadIdx.x;
  const float* pwb = pw + b * Ssz;
  float acc = 0.f;
  for (int s = 0; s < Ssz; ++s) acc += pwb[s] * hf[((u64)(b * Ssz + s)) * Dsz + d];
  pooled[b * Dsz + d] = acc;
}

// ---------------- out[b][n] = sum_k pooled[b][k]*wcls[k][n] ----------------
__global__ __launch_bounds__(256) void k_cls(const float* __restrict__ pooled,
                                             const float* __restrict__ wcls,
                                             float* __restrict__ outp) {
  int n = blockIdx.x * 64 + (threadIdx.x & 63);
  int b = threadIdx.x >> 6;
  const float* pb = pooled + b * Dsz;
  float acc = 0.f;
  for (int k = 0; k < Dsz; ++k) acc += pb[k] * wcls[(u64)k * Ssz + n];
  outp[b * Ssz + n] = acc;
}

extern "C" void kernel_launch(void* const* d_in, const int* in_sizes, int n_in,
                              void* d_out, int out_size, void* d_ws, size_t ws_size,
                              hipStream_t stream) {
  (void)in_sizes; (void)n_in; (void)out_size; (void)ws_size;
  const int*   tokens  = (const int*)  d_in[0];
  const float* tok_emb = (const float*)d_in[1];
  const float* ln1_s   = (const float*)d_in[2];
  const float* ln1_b   = (const float*)d_in[3];
  const float* w_qkv   = (const float*)d_in[4];
  const float* w_proj  = (const float*)d_in[5];
  const float* ln2_s   = (const float*)d_in[6];
  const float* ln2_b   = (const float*)d_in[7];
  const float* w_in    = (const float*)d_in[8];
  const float* w_out   = (const float*)d_in[9];
  const float* lnf_s   = (const float*)d_in[10];
  const float* lnf_b   = (const float*)d_in[11];
  const float* w_score = (const float*)d_in[12];
  const float* w_cls   = (const float*)d_in[13];
  float* outp = (float*)d_out;
  char* ws = (char*)d_ws;

  unsigned short* qkv    = (unsigned short*)(ws + 0);            // 25165824 B
  unsigned short* q_r    = (unsigned short*)(ws + 25165824ull);  // 8388608 B
  unsigned short* k_r    = (unsigned short*)(ws + 33554432ull);  // 8388608 B
  unsigned short* v_t    = (unsigned short*)(ws + 41943040ull);  // 8388608 B
  unsigned short* a_out  = (unsigned short*)(ws + 50331648ull);  // 8388608 B
  float*          hf     = (float*)(ws + 0);                     // 16777216 B (aliases, end of net)
  unsigned short* x_ln   = (unsigned short*)(ws + 67108864ull);  // 8388608 B
  unsigned short* mbuf   = (unsigned short*)(ws + 75497472ull);  // 33554432 B
  float*          h      = (float*)(ws + 109051904ull);          // 16777216 B
  unsigned short* wqkv_t = (unsigned short*)(ws + 125829120ull); // 6291456 B
  unsigned short* wproj_t= (unsigned short*)(ws + 132120576ull); // 2097152 B
  unsigned short* win_t  = (unsigned short*)(ws + 134217728ull); // 16777216 B
  unsigned short* wout_t = (unsigned short*)(ws + 150994944ull); // 8388608 B
  float* cosT    = (float*)(ws + 159383552ull);
  float* sinT    = (float*)(ws + 159514624ull);
  float* scoresb = (float*)(ws + 159645696ull);
  float* pwb     = (float*)(ws + 159662080ull);
  float* pooledb = (float*)(ws + 159678464ull);

  dim3 blk(256);
  k_cossin<<<dim3(128), blk, 0, stream>>>(cosT, sinT);
  k_embed<<<dim3(4096), blk, 0, stream>>>(tokens, tok_emb, h);

  for (int l = 0; l < Ln; ++l) {
    k_layernorm<1><<<dim3(4096), blk, 0, stream>>>(h, ln1_s + l * Dsz, ln1_b + l * Dsz, (void*)x_ln);
    k_wt<<<dim3(96, 32), blk, 0, stream>>>(w_qkv + (u64)l * Dsz * 3 * Dsz, wqkv_t, Dsz, 3 * Dsz);
    k_gemm<1><<<dim3(24, 32), blk, 0, stream>>>(x_ln, wqkv_t, nullptr, (void*)qkv, 4096, 3072, 1024);
    k_rope_heads<<<dim3(16, 16, 4), blk, 0, stream>>>(qkv, cosT, sinT, q_r, k_r, v_t);
    k_attn<<<dim3(16, 16, 4), blk, 0, stream>>>(q_r, k_r, v_t, a_out);
    k_wt<<<dim3(32, 32), blk, 0, stream>>>(w_proj + (u64)l * Dsz * Dsz, wproj_t, Dsz, Dsz);
    k_gemm<2><<<dim3(8, 32), blk, 0, stream>>>(a_out, wproj_t, h, (void*)h, 4096, 1024, 1024);
    k_layernorm<1><<<dim3(4096), blk, 0, stream>>>(h, ln2_s + l * Dsz, ln2_b + l * Dsz, (void*)x_ln);
    k_wt_pair<<<dim3(256, 32), blk, 0, stream>>>(w_in + (u64)l * Dsz * 2 * Fsz, win_t);
    k_gemm<3><<<dim3(64, 32), blk, 0, stream>>>(x_ln, win_t, nullptr, (void*)mbuf, 4096, 8192, 1024);
    k_wt<<<dim3(32, 128), blk, 0, stream>>>(w_out + (u64)l * Fsz * Dsz, wout_t, Fsz, Dsz);
    k_gemm<2><<<dim3(8, 32), blk, 0, stream>>>(mbuf, wout_t, h, (void*)h, 4096, 1024, 4096);
  }

  k_layernorm<0><<<dim3(4096), blk, 0, stream>>>(h, lnf_s, lnf_b, (void*)hf);
  k_scores<<<dim3(1024), blk, 0, stream>>>(hf, w_score, scoresb);
  k_softmax_s<<<dim3(4), blk, 0, stream>>>(scoresb, pwb);
  k_pool<<<dim3(4, 4), blk, 0, stream>>>(hf, pwb, pooledb);
  k_cls<<<dim3(16), blk, 0, stream>>>(pooledb, w_cls, outp);
}

// Round 3
// 2262.761 us; speedup vs baseline: 1.2971x; 1.0338x over previous
//
#include <hip/hip_runtime.h>

#define Bsz 4
#define Ssz 1024
#define Dsz 1024
#define Hn  16
#define DHn 64
#define Ln  6
#define Fsz 4096
#define SCALE_ 0.1767766952966369f  // 1/sqrt(32)

typedef unsigned long long u64;
typedef __attribute__((ext_vector_type(8))) short bf16x8;
typedef __attribute__((ext_vector_type(4))) float f32x4;

__device__ __forceinline__ unsigned short f2bf(float f) {
  union { float f; unsigned int u; } v; v.f = f;
  unsigned int u = v.u + 0x7fffu + ((v.u >> 16) & 1u);
  return (unsigned short)(u >> 16);
}
__device__ __forceinline__ float bf2f(unsigned short h) {
  union { unsigned int u; float f; } v; v.u = ((unsigned int)h) << 16;
  return v.f;
}
__device__ __forceinline__ void gload_lds16(const void* g, void* lds) {
  __builtin_amdgcn_global_load_lds(
      (const __attribute__((address_space(1))) unsigned int*)g,
      (__attribute__((address_space(3))) unsigned int*)lds, 16, 0, 0);
}

// swizzled LDS byte address for a [256][32] bf16 tile stored as 128B paired-row lines
// read of row r, k-slot lq (16B): line=r>>1, u=((r&1)<<2)|lq, slot=u^(line&7)
__device__ __forceinline__ int swz_addr(int r, int lq) {
  int line = r >> 1;
  int u = ((r & 1) << 2) | lq;
  int s = u ^ (line & 7);
  return line * 128 + s * 16;
}

// ---------------- cos/sin tables: [S][32] f32 each ----------------
__global__ __launch_bounds__(256) void k_cossin(float* __restrict__ cosT, float* __restrict__ sinT) {
  int idx = blockIdx.x * 256 + threadIdx.x;
  if (idx >= Ssz * 32) return;
  int s = idx >> 5, i = idx & 31;
  float inv = powf(10000.f, -((float)(2 * i)) / 64.f);
  float f = (float)s * inv;
  cosT[idx] = cosf(f);
  sinT[idx] = sinf(f);
}

// ---------------- embedding gather ----------------
__global__ __launch_bounds__(256) void k_embed(const int* __restrict__ tokens,
                                               const float* __restrict__ emb,
                                               float* __restrict__ h) {
  int rs = blockIdx.x;
  int t = threadIdx.x;
  int tok = tokens[rs];
  *(float4*)&h[(u64)rs * Dsz + t * 4] = *(const float4*)&emb[(u64)tok * Dsz + t * 4];
}

// ---------------- layernorm: 1 row / block ----------------
template <int BF16OUT>
__global__ __launch_bounds__(256) void k_layernorm(const float* __restrict__ x,
                                                   const float* __restrict__ sc,
                                                   const float* __restrict__ bi,
                                                   void* outv) {
  int row = blockIdx.x, t = threadIdx.x;
  const float* xr = x + (u64)row * Dsz;
  float4 v = *(const float4*)&xr[t * 4];
  float sm = v.x + v.y + v.z + v.w;
  float sq = v.x * v.x + v.y * v.y + v.z * v.z + v.w * v.w;
#pragma unroll
  for (int m = 1; m < 64; m <<= 1) { sm += __shfl_xor(sm, m); sq += __shfl_xor(sq, m); }
  __shared__ float r1[4], r2[4];
  if ((t & 63) == 0) { r1[t >> 6] = sm; r2[t >> 6] = sq; }
  __syncthreads();
  sm = r1[0] + r1[1] + r1[2] + r1[3];
  sq = r2[0] + r2[1] + r2[2] + r2[3];
  float mean = sm * (1.f / Dsz);
  float inv = rsqrtf(sq * (1.f / Dsz) - mean * mean + 1e-5f);
  float4 s4 = *(const float4*)&sc[t * 4];
  float4 b4 = *(const float4*)&bi[t * 4];
  float y0 = (v.x - mean) * inv * s4.x + b4.x;
  float y1 = (v.y - mean) * inv * s4.y + b4.y;
  float y2 = (v.z - mean) * inv * s4.z + b4.z;
  float y3 = (v.w - mean) * inv * s4.w + b4.w;
  if (BF16OUT) {
    ushort4 o; o.x = f2bf(y0); o.y = f2bf(y1); o.z = f2bf(y2); o.w = f2bf(y3);
    *(ushort4*)((unsigned short*)outv + (u64)row * Dsz + t * 4) = o;
  } else {
    float4 o; o.x = y0; o.y = y1; o.z = y2; o.w = y3;
    *(float4*)((float*)outv + (u64)row * Dsz + t * 4) = o;
  }
}

// ---------------- weight convert+transpose: f32 [K][N] -> bf16 [N][K] ----------------
__global__ __launch_bounds__(256) void k_wt(const float* __restrict__ in,
                                            unsigned short* __restrict__ out, int K, int N) {
  __shared__ float tile[32][33];
  int nb = blockIdx.x * 32, kb = blockIdx.y * 32;
  int t = threadIdx.x;
  int r = t >> 3, c4 = (t & 7) * 4;
  float4 v = *(const float4*)&in[(u64)(kb + r) * N + nb + c4];
  tile[r][c4] = v.x; tile[r][c4 + 1] = v.y; tile[r][c4 + 2] = v.z; tile[r][c4 + 3] = v.w;
  __syncthreads();
  ushort4 o;
  o.x = f2bf(tile[c4][r]); o.y = f2bf(tile[c4 + 1][r]);
  o.z = f2bf(tile[c4 + 2][r]); o.w = f2bf(tile[c4 + 3][r]);
  *(ushort4*)&out[(u64)(nb + r) * K + kb + c4] = o;
}

// ---- w_in transpose with a/b column interleave: out[n][k] = in[k][(n>>1)+(n&1)*F] ----
__global__ __launch_bounds__(256) void k_wt_pair(const float* __restrict__ in,
                                                 unsigned short* __restrict__ out) {
  __shared__ float tile[32][33];
  int nb = blockIdx.x * 32, kb = blockIdx.y * 32;
  int t = threadIdx.x;
  int r = t >> 3, c4 = (t & 7) * 4;
  int s0 = nb >> 1;
  int srccol = (c4 < 16) ? (s0 + c4) : (Fsz + s0 + (c4 - 16));
  float4 v = *(const float4*)&in[(u64)(kb + r) * (2 * Fsz) + srccol];
  tile[r][c4] = v.x; tile[r][c4 + 1] = v.y; tile[r][c4 + 2] = v.z; tile[r][c4 + 3] = v.w;
  __syncthreads();
  int sc = (r >> 1) + (r & 1) * 16;
  ushort4 o;
  o.x = f2bf(tile[c4][sc]); o.y = f2bf(tile[c4 + 1][sc]);
  o.z = f2bf(tile[c4 + 2][sc]); o.w = f2bf(tile[c4 + 3][sc]);
  *(ushort4*)&out[(u64)(nb + r) * Dsz + kb + c4] = o;
}

// ---------------- 128x128 GEMM (m97 structure) for small-N shapes ----------------
// EPI 0: store f32; EPI 1: store bf16; EPI 2: Cout_f32 = resid + C;
// EPI 3: paired silu-gate
template <int EPI>
__global__ __launch_bounds__(256) void k_gemm(const unsigned short* __restrict__ A,
                                              const unsigned short* __restrict__ Bt,
                                              const float* resid, void* Cout,
                                              int M, int N, int K) {
  __shared__ unsigned short As[128 * 32] __attribute__((aligned(16)));
  __shared__ unsigned short Bs[128 * 32] __attribute__((aligned(16)));
  int t = threadIdx.x, w = t >> 6, l = t & 63;
  int bx = blockIdx.x, by = blockIdx.y;
  int wr = (w >> 1) * 64, wc = (w & 1) * 64;
  int lr = l & 15, lq = l >> 4;
  f32x4 acc[4][4];
#pragma unroll
  for (int i = 0; i < 4; ++i)
#pragma unroll
    for (int j = 0; j < 4; ++j) acc[i][j] = (f32x4){0.f, 0.f, 0.f, 0.f};
  const char* Ab = (const char*)(A + (u64)(by * 128) * K);
  const char* Bb = (const char*)(Bt + (u64)(bx * 128) * K);
  int s0 = t, s1 = t + 256;
  int r0 = s0 >> 2, c0 = s0 & 3, r1 = s1 >> 2, c1 = s1 & 3;
  u64 K2 = (u64)K * 2;
  for (int kt = 0; kt < K; kt += 32) {
    __syncthreads();
    gload_lds16(Ab + (u64)r0 * K2 + (u64)kt * 2 + c0 * 16, (char*)As + s0 * 16);
    gload_lds16(Ab + (u64)r1 * K2 + (u64)kt * 2 + c1 * 16, (char*)As + s1 * 16);
    gload_lds16(Bb + (u64)r0 * K2 + (u64)kt * 2 + c0 * 16, (char*)Bs + s0 * 16);
    gload_lds16(Bb + (u64)r1 * K2 + (u64)kt * 2 + c1 * 16, (char*)Bs + s1 * 16);
    __syncthreads();
    bf16x8 af[4], bfr[4];
#pragma unroll
    for (int mt = 0; mt < 4; ++mt) af[mt] = *(const bf16x8*)&As[(wr + mt * 16 + lr) * 32 + lq * 8];
#pragma unroll
    for (int nt = 0; nt < 4; ++nt) bfr[nt] = *(const bf16x8*)&Bs[(wc + nt * 16 + lr) * 32 + lq * 8];
#pragma unroll
    for (int mt = 0; mt < 4; ++mt)
#pragma unroll
      for (int nt = 0; nt < 4; ++nt)
        acc[mt][nt] = __builtin_amdgcn_mfma_f32_16x16x32_bf16(af[mt], bfr[nt], acc[mt][nt], 0, 0, 0);
  }
#pragma unroll
  for (int mt = 0; mt < 4; ++mt)
#pragma unroll
    for (int nt = 0; nt < 4; ++nt)
#pragma unroll
      for (int r = 0; r < 4; ++r) {
        int row = by * 128 + wr + mt * 16 + lq * 4 + r;
        int col = bx * 128 + wc + nt * 16 + lr;
        float v = acc[mt][nt][r];
        if (EPI == 3) {
          float pv = __shfl_xor(v, 1);
          if ((lr & 1) == 0) {
            float res = v / (1.f + __expf(-v)) * pv;
            ((unsigned short*)Cout)[(u64)row * (N >> 1) + (col >> 1)] = f2bf(res);
          }
        } else {
          u64 idx = (u64)row * N + col;
          if (EPI == 0) ((float*)Cout)[idx] = v;
          else if (EPI == 1) ((unsigned short*)Cout)[idx] = f2bf(v);
          else ((float*)Cout)[idx] = resid[idx] + v;
        }
      }
}

// ---------------- 256x256 deep-pipelined GEMM (BK=32, 4-ring, counted vmcnt) ----------
// 512 threads = 8 waves (2M x 4N); per-wave C = 128x64.
// LDS: 4 rings x (A 16KiB + B 16KiB) = 128 KiB. Stage distance 3 K-tiles.
// EPI 1: store bf16; EPI 3: paired silu-gate (store at col/2, stride N/2)
template <int EPI>
__global__ __launch_bounds__(512, 2) void k_gemm256(const unsigned short* __restrict__ A,
                                                    const unsigned short* __restrict__ Bt,
                                                    void* Cout,
                                                    int M, int N, int K, int NBN) {
  __shared__ char lds[4][32768] __attribute__((aligned(16)));
  int t = threadIdx.x, w = t >> 6, l = t & 63;
  int wm = w >> 2, wn = w & 3;
  int lr = l & 15, lq = l >> 4;
  // bijective XCD swizzle (gridDim.x % 8 == 0)
  int nwg = gridDim.x, bid = blockIdx.x;
  int cpx = nwg >> 3;
  int wg = (bid & 7) * cpx + (bid >> 3);
  int bm = wg / NBN, bn = wg % NBN;
  int NT = K >> 5;
  // staging granule decode: granule g -> line g>>3, slot g&7; u = slot^(line&7);
  // holds G[2*line + (u>>2)][ (u&3)*8 .. +7 ]
  int g0 = t, g1 = t + 512;
  int L0 = g0 >> 3, u0 = (g0 & 7) ^ (L0 & 7), row0 = 2 * L0 + (u0 >> 2), kc0 = (u0 & 3) * 8;
  int L1 = g1 >> 3, u1 = (g1 & 7) ^ (L1 & 7), row1 = 2 * L1 + (u1 >> 2), kc1 = (u1 & 3) * 8;
  const char* Asrc0 = (const char*)(A + (u64)(bm * 256 + row0) * K + kc0);
  const char* Asrc1 = (const char*)(A + (u64)(bm * 256 + row1) * K + kc1);
  const char* Bsrc0 = (const char*)(Bt + (u64)(bn * 256 + row0) * K + kc0);
  const char* Bsrc1 = (const char*)(Bt + (u64)(bn * 256 + row1) * K + kc1);
  f32x4 acc[8][4];
#pragma unroll
  for (int i = 0; i < 8; ++i)
#pragma unroll
    for (int j = 0; j < 4; ++j) acc[i][j] = (f32x4){0.f, 0.f, 0.f, 0.f};
#define STG_A(jj) { char* d_ = lds[(jj) & 3]; \
    gload_lds16(Asrc0 + (u64)(jj) * 64, d_ + g0 * 16); \
    gload_lds16(Asrc1 + (u64)(jj) * 64, d_ + g1 * 16); }
#define STG_B(jj) { char* d_ = lds[(jj) & 3] + 16384; \
    gload_lds16(Bsrc0 + (u64)(jj) * 64, d_ + g0 * 16); \
    gload_lds16(Bsrc1 + (u64)(jj) * 64, d_ + g1 * 16); }
  // prologue: stage tiles 0,1,2 into rings 0,1,2 (12 loads)
  STG_A(0); STG_B(0);
  STG_A(1); STG_B(1);
  STG_A(2); STG_B(2);
  for (int j = 0; j < NT; ++j) {
    if (j < NT - 2)      asm volatile("s_waitcnt vmcnt(8)" ::: "memory");
    else if (j == NT - 2) asm volatile("s_waitcnt vmcnt(4)" ::: "memory");
    else                 asm volatile("s_waitcnt vmcnt(0)" ::: "memory");
    __builtin_amdgcn_s_barrier();
    __builtin_amdgcn_sched_barrier(0);
    const char* Ab = lds[j & 3];
    const char* Bb = lds[j & 3] + 16384;
    bool pf = (j + 3 < NT);
    if (pf) STG_A(j + 3);
    bf16x8 bfrag[4], afrag[4];
#pragma unroll
    for (int ni = 0; ni < 4; ++ni)
      bfrag[ni] = *(const bf16x8*)(Bb + swz_addr(wn * 64 + ni * 16 + lr, lq));
#pragma unroll
    for (int mi = 0; mi < 4; ++mi)
      afrag[mi] = *(const bf16x8*)(Ab + swz_addr(wm * 128 + mi * 16 + lr, lq));
    asm volatile("s_waitcnt lgkmcnt(0)" ::: "memory");
    __builtin_amdgcn_sched_barrier(0);
    __builtin_amdgcn_s_setprio(1);
#pragma unroll
    for (int mi = 0; mi < 4; ++mi)
#pragma unroll
      for (int ni = 0; ni < 4; ++ni)
        acc[mi][ni] = __builtin_amdgcn_mfma_f32_16x16x32_bf16(afrag[mi], bfrag[ni], acc[mi][ni], 0, 0, 0);
    __builtin_amdgcn_s_setprio(0);
    if (pf) STG_B(j + 3);
#pragma unroll
    for (int mi = 0; mi < 4; ++mi)
      afrag[mi] = *(const bf16x8*)(Ab + swz_addr(wm * 128 + (mi + 4) * 16 + lr, lq));
    asm volatile("s_waitcnt lgkmcnt(0)" ::: "memory");
    __builtin_amdgcn_sched_barrier(0);
    __builtin_amdgcn_s_setprio(1);
#pragma unroll
    for (int mi = 0; mi < 4; ++mi)
#pragma unroll
      for (int ni = 0; ni < 4; ++ni)
        acc[mi + 4][ni] = __builtin_amdgcn_mfma_f32_16x16x32_bf16(afrag[mi], bfrag[ni], acc[mi + 4][ni], 0, 0, 0);
    __builtin_amdgcn_s_setprio(0);
  }
#undef STG_A
#undef STG_B
  int crow0 = bm * 256 + wm * 128, ccol0 = bn * 256 + wn * 64;
#pragma unroll
  for (int mi = 0; mi < 8; ++mi)
#pragma unroll
    for (int ni = 0; ni < 4; ++ni)
#pragma unroll
      for (int r = 0; r < 4; ++r) {
        int row = crow0 + mi * 16 + lq * 4 + r;
        int col = ccol0 + ni * 16 + lr;
        float v = acc[mi][ni][r];
        if (EPI == 3) {
          float pv = __shfl_xor(v, 1);
          if ((lr & 1) == 0) {
            float res = v / (1.f + __expf(-v)) * pv;
            ((unsigned short*)Cout)[(u64)row * (N >> 1) + (col >> 1)] = f2bf(res);
          }
        } else {
          ((unsigned short*)Cout)[(u64)row * N + col] = f2bf(v);
        }
      }
}

// ---------------- RoPE + head split + V transpose ----------------
__global__ __launch_bounds__(256) void k_rope_heads(const unsigned short* __restrict__ qkv,
                                                    const float* __restrict__ cosT,
                                                    const float* __restrict__ sinT,
                                                    unsigned short* __restrict__ q_r,
                                                    unsigned short* __restrict__ k_r,
                                                    unsigned short* __restrict__ v_t) {
  int st = blockIdx.x, hh = blockIdx.y, b = blockIdx.z;
  int t = threadIdx.x;
  int r = t >> 2, cg = (t & 3) * 16;
  int s = st * 64 + r;
  u64 rowb = ((u64)(b * Ssz + s)) * (3 * Dsz);
  u64 bh = (u64)(b * Hn + hh);
  const unsigned int* qp = (const unsigned int*)(qkv + rowb + hh * 64 + cg);
  const unsigned int* kp = (const unsigned int*)(qkv + rowb + Dsz + hh * 64 + cg);
  const unsigned short* vp = qkv + rowb + 2 * Dsz + hh * 64 + cg;
  uint4 qv0 = *(const uint4*)qp, qv1 = *(const uint4*)(qp + 4);
  uint4 kv0 = *(const uint4*)kp, kv1 = *(const uint4*)(kp + 4);
  int i0 = s * 32 + (cg >> 1);
  float4 cA0 = *(const float4*)&cosT[i0], cA1 = *(const float4*)&cosT[i0 + 4];
  float4 sA0 = *(const float4*)&sinT[i0], sA1 = *(const float4*)&sinT[i0 + 4];
  unsigned int qw[8] = {qv0.x, qv0.y, qv0.z, qv0.w, qv1.x, qv1.y, qv1.z, qv1.w};
  unsigned int kw[8] = {kv0.x, kv0.y, kv0.z, kv0.w, kv1.x, kv1.y, kv1.z, kv1.w};
  float cA[8] = {cA0.x, cA0.y, cA0.z, cA0.w, cA1.x, cA1.y, cA1.z, cA1.w};
  float sA[8] = {sA0.x, sA0.y, sA0.z, sA0.w, sA1.x, sA1.y, sA1.z, sA1.w};
  unsigned int oq[8], ok[8];
#pragma unroll
  for (int j = 0; j < 8; ++j) {
    float c = cA[j], sn = sA[j];
    float qe = bf2f((unsigned short)(qw[j] & 0xffff)), qo = bf2f((unsigned short)(qw[j] >> 16));
    float ke = bf2f((unsigned short)(kw[j] & 0xffff)), ko = bf2f((unsigned short)(kw[j] >> 16));
    oq[j] = (unsigned int)f2bf(qe * c - qo * sn) | ((unsigned int)f2bf(qo * c + qe * sn) << 16);
    ok[j] = (unsigned int)f2bf(ke * c - ko * sn) | ((unsigned int)f2bf(ko * c + ke * sn) << 16);
  }
  u64 dst = (bh * Ssz + s) * 64 + cg;
  uint4 a0; a0.x = oq[0]; a0.y = oq[1]; a0.z = oq[2]; a0.w = oq[3];
  uint4 a1; a1.x = oq[4]; a1.y = oq[5]; a1.z = oq[6]; a1.w = oq[7];
  ((uint4*)&q_r[dst])[0] = a0; ((uint4*)&q_r[dst])[1] = a1;
  uint4 b0; b0.x = ok[0]; b0.y = ok[1]; b0.z = ok[2]; b0.w = ok[3];
  uint4 b1; b1.x = ok[4]; b1.y = ok[5]; b1.z = ok[6]; b1.w = ok[7];
  ((uint4*)&k_r[dst])[0] = b0; ((uint4*)&k_r[dst])[1] = b1;
  __shared__ unsigned short vt_lds[64][65];
  uint4 vv0 = *(const uint4*)vp, vv1 = *(const uint4*)(vp + 8);
  unsigned int vw[8] = {vv0.x, vv0.y, vv0.z, vv0.w, vv1.x, vv1.y, vv1.z, vv1.w};
#pragma unroll
  for (int j = 0; j < 8; ++j) {
    vt_lds[r][cg + 2 * j] = (unsigned short)(vw[j] & 0xffff);
    vt_lds[r][cg + 2 * j + 1] = (unsigned short)(vw[j] >> 16);
  }
  __syncthreads();
  unsigned int ov[8];
#pragma unroll
  for (int j = 0; j < 8; ++j) {
    unsigned short lo = vt_lds[cg + 2 * j][r], hi = vt_lds[cg + 2 * j + 1][r];
    ov[j] = (unsigned int)lo | ((unsigned int)hi << 16);
  }
  u64 vdst = bh * ((u64)DHn * Ssz) + (u64)r * Ssz + st * 64 + cg;
  uint4 c0v; c0v.x = ov[0]; c0v.y = ov[1]; c0v.z = ov[2]; c0v.w = ov[3];
  uint4 c1v; c1v.x = ov[4]; c1v.y = ov[5]; c1v.z = ov[6]; c1v.w = ov[7];
  ((uint4*)&v_t[vdst])[0] = c0v; ((uint4*)&v_t[vdst])[1] = c1v;
}

// ---------------- fused attention (LDS-staged K/V, swapped QK^T) ----------------
__global__ __launch_bounds__(256) void k_attn(const unsigned short* __restrict__ qr,
                                              const unsigned short* __restrict__ kr,
                                              const unsigned short* __restrict__ vt,
                                              unsigned short* __restrict__ outp) {
  __shared__ unsigned short Klds[2][2][64 * 32] __attribute__((aligned(16)));
  __shared__ unsigned short Vlds[2][2][64 * 32] __attribute__((aligned(16)));
  __shared__ unsigned short Plds[4][16 * 64] __attribute__((aligned(16)));
  int qt = blockIdx.x, hh = blockIdx.y, b = blockIdx.z;
  int t = threadIdx.x, w = t >> 6, l = t & 63;
  int lr = l & 15, lq = l >> 4;
  u64 bh = (u64)(b * Hn + hh);
  const unsigned short* Qp = qr + bh * (Ssz * DHn);
  const unsigned short* Kp = kr + bh * (Ssz * DHn);
  const unsigned short* Vp = vt + bh * ((u64)DHn * Ssz);
  int q0 = qt * 64 + w * 16;
  bf16x8 qlo = *(const bf16x8*)&Qp[(q0 + lr) * DHn + lq * 8];
  bf16x8 qhi = *(const bf16x8*)&Qp[(q0 + lr) * DHn + 32 + lq * 8];
  int srow = t >> 2;
  int scol8 = (t & 3) * 8;
#define STAGEKV(bufi, kbase)                                                         \
  do {                                                                               \
    gload_lds16(&Kp[((kbase) + srow) * 64 + scol8],      (char*)&Klds[bufi][0][0] + t * 16); \
    gload_lds16(&Kp[((kbase) + srow) * 64 + 32 + scol8], (char*)&Klds[bufi][1][0] + t * 16); \
    gload_lds16(&Vp[(u64)srow * Ssz + (kbase) + scol8],      (char*)&Vlds[bufi][0][0] + t * 16); \
    gload_lds16(&Vp[(u64)srow * Ssz + (kbase) + 32 + scol8], (char*)&Vlds[bufi][1][0] + t * 16); \
  } while (0)
  float m_col = -1e30f, lsum = 0.f;
  float m_row[4] = {-1e30f, -1e30f, -1e30f, -1e30f};
  f32x4 o[4];
#pragma unroll
  for (int r = 0; r < 4; ++r) o[r] = (f32x4){0.f, 0.f, 0.f, 0.f};
  char* Pw = (char*)&Plds[w][0];

  STAGEKV(0, 0);
  asm volatile("s_waitcnt vmcnt(0)" ::: "memory");
  __syncthreads();
  int buf = 0;
  for (int kb = 0; kb < Ssz; kb += 64) {
    if (kb + 64 < Ssz) STAGEKV(buf ^ 1, kb + 64);
    float p[4][4];
#pragma unroll
    for (int ct = 0; ct < 4; ++ct) {
      bf16x8 klo = *(const bf16x8*)&Klds[buf][0][(ct * 16 + lr) * 32 + lq * 8];
      bf16x8 khi = *(const bf16x8*)&Klds[buf][1][(ct * 16 + lr) * 32 + lq * 8];
      f32x4 z = (f32x4){0.f, 0.f, 0.f, 0.f};
      f32x4 slo = __builtin_amdgcn_mfma_f32_16x16x32_bf16(klo, qlo, z, 0, 0, 0);
      f32x4 shi = __builtin_amdgcn_mfma_f32_16x16x32_bf16(khi, qhi, z, 0, 0, 0);
      int kg0 = kb + ct * 16 + lq * 4;
      int qg = q0 + lr;
#pragma unroll
      for (int r = 0; r < 4; ++r) p[ct][r] = (kg0 + r <= qg ? shi[r] : slo[r]) * SCALE_;
    }
    float tm = p[0][0];
#pragma unroll
    for (int ct = 0; ct < 4; ++ct)
#pragma unroll
      for (int r = 0; r < 4; ++r) tm = fmaxf(tm, p[ct][r]);
    tm = fmaxf(tm, __shfl_xor(tm, 16));
    tm = fmaxf(tm, __shfl_xor(tm, 32));
    float m_new = fmaxf(m_col, tm);
    lsum *= __expf(m_col - m_new);
    m_col = m_new;
#pragma unroll
    for (int r = 0; r < 4; ++r) {
      float mr = __shfl(m_col, lq * 4 + r);
      float scf = __expf(m_row[r] - mr);
      m_row[r] = mr;
      o[0][r] *= scf; o[1][r] *= scf; o[2][r] *= scf; o[3][r] *= scf;
    }
#pragma unroll
    for (int ct = 0; ct < 4; ++ct) {
      float e0 = __expf(p[ct][0] - m_col);
      float e1 = __expf(p[ct][1] - m_col);
      float e2 = __expf(p[ct][2] - m_col);
      float e3 = __expf(p[ct][3] - m_col);
      lsum += e0 + e1 + e2 + e3;
      ushort4 pk; pk.x = f2bf(e0); pk.y = f2bf(e1); pk.z = f2bf(e2); pk.w = f2bf(e3);
      int byte_ = (lr * 128 + ct * 32 + lq * 8) ^ ((lr & 7) << 4);
      *(ushort4*)(Pw + byte_) = pk;
    }
    asm volatile("s_waitcnt lgkmcnt(0)" ::: "memory");
    __builtin_amdgcn_sched_barrier(0);
#pragma unroll
    for (int ks = 0; ks < 2; ++ks) {
      int pb = (lr * 128 + ks * 64 + lq * 16) ^ ((lr & 7) << 4);
      bf16x8 pa = *(const bf16x8*)(Pw + pb);
#pragma unroll
      for (int nt = 0; nt < 4; ++nt) {
        bf16x8 vb = *(const bf16x8*)&Vlds[buf][ks][(nt * 16 + lr) * 32 + lq * 8];
        o[nt] = __builtin_amdgcn_mfma_f32_16x16x32_bf16(pa, vb, o[nt], 0, 0, 0);
      }
    }
    asm volatile("s_waitcnt vmcnt(0)" ::: "memory");
    __syncthreads();
    buf ^= 1;
  }
  lsum += __shfl_xor(lsum, 16);
  lsum += __shfl_xor(lsum, 32);
  u64 obase = ((u64)b * Ssz) * Dsz + (u64)hh * DHn;
#pragma unroll
  for (int r = 0; r < 4; ++r) {
    float ls = __shfl(lsum, lq * 4 + r);
    float inv = 1.f / ls;
    int qrow = q0 + lq * 4 + r;
#pragma unroll
    for (int nt = 0; nt < 4; ++nt)
      outp[obase + (u64)qrow * Dsz + nt * 16 + lr] = f2bf(o[nt][r] * inv);
  }
#undef STAGEKV
}

// ---------------- scores = hf @ w_score ----------------
__global__ __launch_bounds__(256) void k_scores(const float* __restrict__ hf,
                                                const float* __restrict__ wsc,
                                                float* __restrict__ scores) {
  int row = blockIdx.x * 4 + (threadIdx.x >> 6);
  int l = threadIdx.x & 63;
  const float* xr = hf + (u64)row * Dsz;
  float acc = 0.f;
#pragma unroll
  for (int j = 0; j < 4; ++j) {
    float4 v = *(const float4*)&xr[(j * 64 + l) * 4];
    float4 ww = *(const float4*)&wsc[(j * 64 + l) * 4];
    acc += v.x * ww.x + v.y * ww.y + v.z * ww.z + v.w * ww.w;
  }
#pragma unroll
  for (int m = 1; m < 64; m <<= 1) acc += __shfl_xor(acc, m);
  if (l == 0) scores[row] = acc;
}

// ---------------- softmax over S (per batch) ----------------
__global__ __launch_bounds__(256) void k_softmax_s(const float* __restrict__ sc,
                                                   float* __restrict__ pw) {
  int b = blockIdx.x, t = threadIdx.x;
  const float* sr = sc + b * Ssz;
  float4 v = *(const float4*)&sr[t * 4];
  float mx = fmaxf(fmaxf(v.x, v.y), fmaxf(v.z, v.w));
#pragma unroll
  for (int m = 1; m < 64; m <<= 1) mx = fmaxf(mx, __shfl_xor(mx, m));
  __shared__ float red[4];
  if ((t & 63) == 0) red[t >> 6] = mx;
  __syncthreads();
  mx = fmaxf(fmaxf(red[0], red[1]), fmaxf(red[2], red[3]));
  float e0 = __expf(v.x - mx), e1 = __expf(v.y - mx), e2 = __expf(v.z - mx), e3 = __expf(v.w - mx);
  float sm = e0 + e1 + e2 + e3;
#pragma unroll
  for (int m = 1; m < 64; m <<= 1) sm += __shfl_xor(sm, m);
  __shared__ float red2[4];
  if ((t & 63) == 0) red2[t >> 6] = sm;
  __syncthreads();
  sm = red2[0] + red2[1] + red2[2] + red2[3];
  float inv = 1.f / sm;
  float4 o; o.x = e0 * inv; o.y = e1 * inv; o.z = e2 * inv; o.w = e3 * inv;
  *(float4*)&pw[b * Ssz + t * 4] = o;
}

// ---------------- pooled[b][d] = sum_s pw[b][s]*hf[b][s][d] ----------------
__global__ __launch_bounds__(256) void k_pool(const float* __restrict__ hf,
                                              const float* __restrict__ pw,
                                              float* __restrict__ pooled) {
  int b = blockIdx.y;
  int d = blockIdx.x * 256 + threadIdx.x;
  const float* pwb = pw + b * Ssz;
  float acc = 0.f;
  for (int s = 0; s < Ssz; ++s) acc += pwb[s] * hf[((u64)(b * Ssz + s)) * Dsz + d];
  pooled[b * Dsz + d] = acc;
}

// ---------------- out[b][n] = sum_k pooled[b][k]*wcls[k][n] ----------------
__global__ __launch_bounds__(256) void k_cls(const float* __restrict__ pooled,
                                             const float* __restrict__ wcls,
                                             float* __restrict__ outp) {
  int n = blockIdx.x * 64 + (threadIdx.x & 63);
  int b = threadIdx.x >> 6;
  const float* pb = pooled + b * Dsz;
  float acc = 0.f;
  for (int k = 0; k < Dsz; ++k) acc += pb[k] * wcls[(u64)k * Ssz + n];
  outp[b * Ssz + n] = acc;
}

extern "C" void kernel_launch(void* const* d_in, const int* in_sizes, int n_in,
                              void* d_out, int out_size, void* d_ws, size_t ws_size,
                              hipStream_t stream) {
  (void)in_sizes; (void)n_in; (void)out_size; (void)ws_size;
  const int*   tokens  = (const int*)  d_in[0];
  const float* tok_emb = (const float*)d_in[1];
  const float* ln1_s   = (const float*)d_in[2];
  const float* ln1_b   = (const float*)d_in[3];
  const float* w_qkv   = (const float*)d_in[4];
  const float* w_proj  = (const float*)d_in[5];
  const float* ln2_s   = (const float*)d_in[6];
  const float* ln2_b   = (const float*)d_in[7];
  const float* w_in    = (const float*)d_in[8];
  const float* w_out   = (const float*)d_in[9];
  const float* lnf_s   = (const float*)d_in[10];
  const float* lnf_b   = (const float*)d_in[11];
  const float* w_score = (const float*)d_in[12];
  const float* w_cls   = (const float*)d_in[13];
  float* outp = (float*)d_out;
  char* ws = (char*)d_ws;

  unsigned short* qkv    = (unsigned short*)(ws + 0);
  unsigned short* q_r    = (unsigned short*)(ws + 25165824ull);
  unsigned short* k_r    = (unsigned short*)(ws + 33554432ull);
  unsigned short* v_t    = (unsigned short*)(ws + 41943040ull);
  unsigned short* a_out  = (unsigned short*)(ws + 50331648ull);
  float*          hf     = (float*)(ws + 0);
  unsigned short* x_ln   = (unsigned short*)(ws + 67108864ull);
  unsigned short* mbuf   = (unsigned short*)(ws + 75497472ull);
  float*          h      = (float*)(ws + 109051904ull);
  unsigned short* wqkv_t = (unsigned short*)(ws + 125829120ull);
  unsigned short* wproj_t= (unsigned short*)(ws + 132120576ull);
  unsigned short* win_t  = (unsigned short*)(ws + 134217728ull);
  unsigned short* wout_t = (unsigned short*)(ws + 150994944ull);
  float* cosT    = (float*)(ws + 159383552ull);
  float* sinT    = (float*)(ws + 159514624ull);
  float* scoresb = (float*)(ws + 159645696ull);
  float* pwb     = (float*)(ws + 159662080ull);
  float* pooledb = (float*)(ws + 159678464ull);

  dim3 blk(256);
  k_cossin<<<dim3(128), blk, 0, stream>>>(cosT, sinT);
  k_embed<<<dim3(4096), blk, 0, stream>>>(tokens, tok_emb, h);

  for (int l = 0; l < Ln; ++l) {
    k_layernorm<1><<<dim3(4096), blk, 0, stream>>>(h, ln1_s + l * Dsz, ln1_b + l * Dsz, (void*)x_ln);
    k_wt<<<dim3(96, 32), blk, 0, stream>>>(w_qkv + (u64)l * Dsz * 3 * Dsz, wqkv_t, Dsz, 3 * Dsz);
    k_gemm256<1><<<dim3(192), dim3(512), 0, stream>>>(x_ln, wqkv_t, (void*)qkv, 4096, 3072, 1024, 12);
    k_rope_heads<<<dim3(16, 16, 4), blk, 0, stream>>>(qkv, cosT, sinT, q_r, k_r, v_t);
    k_attn<<<dim3(16, 16, 4), blk, 0, stream>>>(q_r, k_r, v_t, a_out);
    k_wt<<<dim3(32, 32), blk, 0, stream>>>(w_proj + (u64)l * Dsz * Dsz, wproj_t, Dsz, Dsz);
    k_gemm<2><<<dim3(8, 32), blk, 0, stream>>>(a_out, wproj_t, h, (void*)h, 4096, 1024, 1024);
    k_layernorm<1><<<dim3(4096), blk, 0, stream>>>(h, ln2_s + l * Dsz, ln2_b + l * Dsz, (void*)x_ln);
    k_wt_pair<<<dim3(256, 32), blk, 0, stream>>>(w_in + (u64)l * Dsz * 2 * Fsz, win_t);
    k_gemm256<3><<<dim3(512), dim3(512), 0, stream>>>(x_ln, win_t, (void*)mbuf, 4096, 8192, 1024, 32);
    k_wt<<<dim3(32, 128), blk, 0, stream>>>(w_out + (u64)l * Fsz * Dsz, wout_t, Fsz, Dsz);
    k_gemm<2><<<dim3(8, 32), blk, 0, stream>>>(mbuf, wout_t, h, (void*)h, 4096, 1024, 4096);
  }

  k_layernorm<0><<<dim3(4096), blk, 0, stream>>>(h, lnf_s, lnf_b, (void*)hf);
  k_scores<<<dim3(1024), blk, 0, stream>>>(hf, w_score, scoresb);
  k_softmax_s<<<dim3(4), blk, 0, stream>>>(scoresb, pwb);
  k_pool<<<dim3(4, 4), blk, 0, stream>>>(hf, pwb, pooledb);
  k_cls<<<dim3(16), blk, 0, stream>>>(pooledb, w_cls, outp);
}

// Round 4
// 1989.300 us; speedup vs baseline: 1.4754x; 1.1375x over previous
//
#include <hip/hip_runtime.h>

#define Bsz 4
#define Ssz 1024
#define Dsz 1024
#define Hn  16
#define DHn 64
#define Ln  6
#define Fsz 4096
#define SCALE_ 0.1767766952966369f  // 1/sqrt(32)

typedef unsigned long long u64;
typedef __attribute__((ext_vector_type(8))) short bf16x8;
typedef __attribute__((ext_vector_type(4))) float f32x4;

__device__ __forceinline__ unsigned short f2bf(float f) {
  union { float f; unsigned int u; } v; v.f = f;
  unsigned int u = v.u + 0x7fffu + ((v.u >> 16) & 1u);
  return (unsigned short)(u >> 16);
}
__device__ __forceinline__ float bf2f(unsigned short h) {
  union { unsigned int u; float f; } v; v.u = ((unsigned int)h) << 16;
  return v.f;
}
__device__ __forceinline__ void gload_lds16(const void* g, void* lds) {
  __builtin_amdgcn_global_load_lds(
      (const __attribute__((address_space(1))) unsigned int*)g,
      (__attribute__((address_space(3))) unsigned int*)lds, 16, 0, 0);
}

// swizzled LDS byte address for [R][32] bf16 tiles stored as 128B paired-row lines
// read of row r, k-slot lq (16B): line=r>>1, u=((r&1)<<2)|lq, slot=u^(line&7)
__device__ __forceinline__ int swz_addr(int r, int lq) {
  int line = r >> 1;
  int u = ((r & 1) << 2) | lq;
  int s = u ^ (line & 7);
  return line * 128 + s * 16;
}

// ---------------- cos/sin tables: [S][32] f32 each ----------------
__global__ __launch_bounds__(256) void k_cossin(float* __restrict__ cosT, float* __restrict__ sinT) {
  int idx = blockIdx.x * 256 + threadIdx.x;
  if (idx >= Ssz * 32) return;
  int s = idx >> 5, i = idx & 31;
  float inv = powf(10000.f, -((float)(2 * i)) / 64.f);
  float f = (float)s * inv;
  cosT[idx] = cosf(f);
  sinT[idx] = sinf(f);
}

// ---------------- embedding gather ----------------
__global__ __launch_bounds__(256) void k_embed(const int* __restrict__ tokens,
                                               const float* __restrict__ emb,
                                               float* __restrict__ h) {
  int rs = blockIdx.x;
  int t = threadIdx.x;
  int tok = tokens[rs];
  *(float4*)&h[(u64)rs * Dsz + t * 4] = *(const float4*)&emb[(u64)tok * Dsz + t * 4];
}

// ---------------- layernorm: 1 row / block ----------------
template <int BF16OUT>
__global__ __launch_bounds__(256) void k_layernorm(const float* __restrict__ x,
                                                   const float* __restrict__ sc,
                                                   const float* __restrict__ bi,
                                                   void* outv) {
  int row = blockIdx.x, t = threadIdx.x;
  const float* xr = x + (u64)row * Dsz;
  float4 v = *(const float4*)&xr[t * 4];
  float sm = v.x + v.y + v.z + v.w;
  float sq = v.x * v.x + v.y * v.y + v.z * v.z + v.w * v.w;
#pragma unroll
  for (int m = 1; m < 64; m <<= 1) { sm += __shfl_xor(sm, m); sq += __shfl_xor(sq, m); }
  __shared__ float r1[4], r2[4];
  if ((t & 63) == 0) { r1[t >> 6] = sm; r2[t >> 6] = sq; }
  __syncthreads();
  sm = r1[0] + r1[1] + r1[2] + r1[3];
  sq = r2[0] + r2[1] + r2[2] + r2[3];
  float mean = sm * (1.f / Dsz);
  float inv = rsqrtf(sq * (1.f / Dsz) - mean * mean + 1e-5f);
  float4 s4 = *(const float4*)&sc[t * 4];
  float4 b4 = *(const float4*)&bi[t * 4];
  float y0 = (v.x - mean) * inv * s4.x + b4.x;
  float y1 = (v.y - mean) * inv * s4.y + b4.y;
  float y2 = (v.z - mean) * inv * s4.z + b4.z;
  float y3 = (v.w - mean) * inv * s4.w + b4.w;
  if (BF16OUT) {
    ushort4 o; o.x = f2bf(y0); o.y = f2bf(y1); o.z = f2bf(y2); o.w = f2bf(y3);
    *(ushort4*)((unsigned short*)outv + (u64)row * Dsz + t * 4) = o;
  } else {
    float4 o; o.x = y0; o.y = y1; o.z = y2; o.w = y3;
    *(float4*)((float*)outv + (u64)row * Dsz + t * 4) = o;
  }
}

// ---------------- weight convert+transpose: f32 [K][N] -> bf16 [N][K] ----------------
__global__ __launch_bounds__(256) void k_wt(const float* __restrict__ in,
                                            unsigned short* __restrict__ out, int K, int N) {
  __shared__ float tile[32][33];
  int nb = blockIdx.x * 32, kb = blockIdx.y * 32;
  int t = threadIdx.x;
  int r = t >> 3, c4 = (t & 7) * 4;
  float4 v = *(const float4*)&in[(u64)(kb + r) * N + nb + c4];
  tile[r][c4] = v.x; tile[r][c4 + 1] = v.y; tile[r][c4 + 2] = v.z; tile[r][c4 + 3] = v.w;
  __syncthreads();
  ushort4 o;
  o.x = f2bf(tile[c4][r]); o.y = f2bf(tile[c4 + 1][r]);
  o.z = f2bf(tile[c4 + 2][r]); o.w = f2bf(tile[c4 + 3][r]);
  *(ushort4*)&out[(u64)(nb + r) * K + kb + c4] = o;
}

// ---- w_in transpose with a/b column interleave: out[n][k] = in[k][(n>>1)+(n&1)*F] ----
__global__ __launch_bounds__(256) void k_wt_pair(const float* __restrict__ in,
                                                 unsigned short* __restrict__ out) {
  __shared__ float tile[32][33];
  int nb = blockIdx.x * 32, kb = blockIdx.y * 32;
  int t = threadIdx.x;
  int r = t >> 3, c4 = (t & 7) * 4;
  int s0 = nb >> 1;
  int srccol = (c4 < 16) ? (s0 + c4) : (Fsz + s0 + (c4 - 16));
  float4 v = *(const float4*)&in[(u64)(kb + r) * (2 * Fsz) + srccol];
  tile[r][c4] = v.x; tile[r][c4 + 1] = v.y; tile[r][c4 + 2] = v.z; tile[r][c4 + 3] = v.w;
  __syncthreads();
  int sc = (r >> 1) + (r & 1) * 16;
  ushort4 o;
  o.x = f2bf(tile[c4][sc]); o.y = f2bf(tile[c4 + 1][sc]);
  o.z = f2bf(tile[c4 + 2][sc]); o.w = f2bf(tile[c4 + 3][sc]);
  *(ushort4*)&out[(u64)(nb + r) * Dsz + kb + c4] = o;
}

// ---------------- 128x128 ring-pipelined GEMM (BK=32, 4-ring, counted vmcnt) --------
// 256 threads = 4 waves (2M x 2N); per-wave C = 64x64. LDS 4 rings x 16KiB = 64KiB
// -> 2 blocks/CU. EPI 1: store bf16; EPI 2: Cout_f32 = resid + C
template <int EPI>
__global__ __launch_bounds__(256, 2) void k_ring128(const unsigned short* __restrict__ A,
                                                    const unsigned short* __restrict__ Bt,
                                                    const float* resid, void* Cout,
                                                    int M, int N, int K) {
  __shared__ char lds[4][16384] __attribute__((aligned(16)));
  int t = threadIdx.x, w = t >> 6, l = t & 63;
  int wm = w >> 1, wn = w & 1;
  int lr = l & 15, lq = l >> 4;
  int bn = blockIdx.x, bm = blockIdx.y;
  int NT = K >> 5;
  // staging granule decode (pre-swizzled global source, linear LDS dest)
  int g0 = t, g1 = t + 256;
  int L0 = g0 >> 3, u0 = (g0 & 7) ^ (L0 & 7), row0 = 2 * L0 + (u0 >> 2), kc0 = (u0 & 3) * 8;
  int L1 = g1 >> 3, u1 = (g1 & 7) ^ (L1 & 7), row1 = 2 * L1 + (u1 >> 2), kc1 = (u1 & 3) * 8;
  const char* Asrc0 = (const char*)(A + (u64)(bm * 128 + row0) * K + kc0);
  const char* Asrc1 = (const char*)(A + (u64)(bm * 128 + row1) * K + kc1);
  const char* Bsrc0 = (const char*)(Bt + (u64)(bn * 128 + row0) * K + kc0);
  const char* Bsrc1 = (const char*)(Bt + (u64)(bn * 128 + row1) * K + kc1);
  f32x4 acc[4][4];
#pragma unroll
  for (int i = 0; i < 4; ++i)
#pragma unroll
    for (int j = 0; j < 4; ++j) acc[i][j] = (f32x4){0.f, 0.f, 0.f, 0.f};
#define STG128(jj) { char* d_ = lds[(jj) & 3]; \
    gload_lds16(Asrc0 + (u64)(jj) * 64, d_ + g0 * 16); \
    gload_lds16(Asrc1 + (u64)(jj) * 64, d_ + g1 * 16); \
    gload_lds16(Bsrc0 + (u64)(jj) * 64, d_ + 8192 + g0 * 16); \
    gload_lds16(Bsrc1 + (u64)(jj) * 64, d_ + 8192 + g1 * 16); }
  STG128(0); STG128(1); STG128(2);
  for (int j = 0; j < NT; ++j) {
    if (j < NT - 2)       asm volatile("s_waitcnt vmcnt(8)" ::: "memory");
    else if (j == NT - 2) asm volatile("s_waitcnt vmcnt(4)" ::: "memory");
    else                  asm volatile("s_waitcnt vmcnt(0)" ::: "memory");
    __builtin_amdgcn_s_barrier();
    __builtin_amdgcn_sched_barrier(0);
    const char* Ab = lds[j & 3];
    const char* Bb = lds[j & 3] + 8192;
    if (j + 3 < NT) STG128(j + 3);
    bf16x8 afrag[4], bfrag[4];
#pragma unroll
    for (int ni = 0; ni < 4; ++ni)
      bfrag[ni] = *(const bf16x8*)(Bb + swz_addr(wn * 64 + ni * 16 + lr, lq));
#pragma unroll
    for (int mi = 0; mi < 4; ++mi)
      afrag[mi] = *(const bf16x8*)(Ab + swz_addr(wm * 64 + mi * 16 + lr, lq));
    asm volatile("s_waitcnt lgkmcnt(0)" ::: "memory");
    __builtin_amdgcn_sched_barrier(0);
    __builtin_amdgcn_s_setprio(1);
#pragma unroll
    for (int mi = 0; mi < 4; ++mi)
#pragma unroll
      for (int ni = 0; ni < 4; ++ni)
        acc[mi][ni] = __builtin_amdgcn_mfma_f32_16x16x32_bf16(afrag[mi], bfrag[ni], acc[mi][ni], 0, 0, 0);
    __builtin_amdgcn_s_setprio(0);
  }
#undef STG128
#pragma unroll
  for (int mi = 0; mi < 4; ++mi)
#pragma unroll
    for (int ni = 0; ni < 4; ++ni)
#pragma unroll
      for (int r = 0; r < 4; ++r) {
        int row = bm * 128 + wm * 64 + mi * 16 + lq * 4 + r;
        int col = bn * 128 + wn * 64 + ni * 16 + lr;
        u64 idx = (u64)row * N + col;
        float v = acc[mi][ni][r];
        if (EPI == 1) ((unsigned short*)Cout)[idx] = f2bf(v);
        else ((float*)Cout)[idx] = resid[idx] + v;
      }
}

// ---------------- 256x256 deep-pipelined GEMM (BK=32, 4-ring, counted vmcnt) ----------
template <int EPI>
__global__ __launch_bounds__(512, 2) void k_gemm256(const unsigned short* __restrict__ A,
                                                    const unsigned short* __restrict__ Bt,
                                                    void* Cout,
                                                    int M, int N, int K, int NBN) {
  __shared__ char lds[4][32768] __attribute__((aligned(16)));
  int t = threadIdx.x, w = t >> 6, l = t & 63;
  int wm = w >> 2, wn = w & 3;
  int lr = l & 15, lq = l >> 4;
  int nwg = gridDim.x, bid = blockIdx.x;
  int cpx = nwg >> 3;
  int wg = (bid & 7) * cpx + (bid >> 3);
  int bm = wg / NBN, bn = wg % NBN;
  int NT = K >> 5;
  int g0 = t, g1 = t + 512;
  int L0 = g0 >> 3, u0 = (g0 & 7) ^ (L0 & 7), row0 = 2 * L0 + (u0 >> 2), kc0 = (u0 & 3) * 8;
  int L1 = g1 >> 3, u1 = (g1 & 7) ^ (L1 & 7), row1 = 2 * L1 + (u1 >> 2), kc1 = (u1 & 3) * 8;
  const char* Asrc0 = (const char*)(A + (u64)(bm * 256 + row0) * K + kc0);
  const char* Asrc1 = (const char*)(A + (u64)(bm * 256 + row1) * K + kc1);
  const char* Bsrc0 = (const char*)(Bt + (u64)(bn * 256 + row0) * K + kc0);
  const char* Bsrc1 = (const char*)(Bt + (u64)(bn * 256 + row1) * K + kc1);
  f32x4 acc[8][4];
#pragma unroll
  for (int i = 0; i < 8; ++i)
#pragma unroll
    for (int j = 0; j < 4; ++j) acc[i][j] = (f32x4){0.f, 0.f, 0.f, 0.f};
#define STG_A(jj) { char* d_ = lds[(jj) & 3]; \
    gload_lds16(Asrc0 + (u64)(jj) * 64, d_ + g0 * 16); \
    gload_lds16(Asrc1 + (u64)(jj) * 64, d_ + g1 * 16); }
#define STG_B(jj) { char* d_ = lds[(jj) & 3] + 16384; \
    gload_lds16(Bsrc0 + (u64)(jj) * 64, d_ + g0 * 16); \
    gload_lds16(Bsrc1 + (u64)(jj) * 64, d_ + g1 * 16); }
  STG_A(0); STG_B(0);
  STG_A(1); STG_B(1);
  STG_A(2); STG_B(2);
  for (int j = 0; j < NT; ++j) {
    if (j < NT - 2)       asm volatile("s_waitcnt vmcnt(8)" ::: "memory");
    else if (j == NT - 2) asm volatile("s_waitcnt vmcnt(4)" ::: "memory");
    else                  asm volatile("s_waitcnt vmcnt(0)" ::: "memory");
    __builtin_amdgcn_s_barrier();
    __builtin_amdgcn_sched_barrier(0);
    const char* Ab = lds[j & 3];
    const char* Bb = lds[j & 3] + 16384;
    bool pf = (j + 3 < NT);
    if (pf) STG_A(j + 3);
    bf16x8 bfrag[4], afrag[4];
#pragma unroll
    for (int ni = 0; ni < 4; ++ni)
      bfrag[ni] = *(const bf16x8*)(Bb + swz_addr(wn * 64 + ni * 16 + lr, lq));
#pragma unroll
    for (int mi = 0; mi < 4; ++mi)
      afrag[mi] = *(const bf16x8*)(Ab + swz_addr(wm * 128 + mi * 16 + lr, lq));
    asm volatile("s_waitcnt lgkmcnt(0)" ::: "memory");
    __builtin_amdgcn_sched_barrier(0);
    __builtin_amdgcn_s_setprio(1);
#pragma unroll
    for (int mi = 0; mi < 4; ++mi)
#pragma unroll
      for (int ni = 0; ni < 4; ++ni)
        acc[mi][ni] = __builtin_amdgcn_mfma_f32_16x16x32_bf16(afrag[mi], bfrag[ni], acc[mi][ni], 0, 0, 0);
    __builtin_amdgcn_s_setprio(0);
    if (pf) STG_B(j + 3);
#pragma unroll
    for (int mi = 0; mi < 4; ++mi)
      afrag[mi] = *(const bf16x8*)(Ab + swz_addr(wm * 128 + (mi + 4) * 16 + lr, lq));
    asm volatile("s_waitcnt lgkmcnt(0)" ::: "memory");
    __builtin_amdgcn_sched_barrier(0);
    __builtin_amdgcn_s_setprio(1);
#pragma unroll
    for (int mi = 0; mi < 4; ++mi)
#pragma unroll
      for (int ni = 0; ni < 4; ++ni)
        acc[mi + 4][ni] = __builtin_amdgcn_mfma_f32_16x16x32_bf16(afrag[mi], bfrag[ni], acc[mi + 4][ni], 0, 0, 0);
    __builtin_amdgcn_s_setprio(0);
  }
#undef STG_A
#undef STG_B
  int crow0 = bm * 256 + wm * 128, ccol0 = bn * 256 + wn * 64;
#pragma unroll
  for (int mi = 0; mi < 8; ++mi)
#pragma unroll
    for (int ni = 0; ni < 4; ++ni)
#pragma unroll
      for (int r = 0; r < 4; ++r) {
        int row = crow0 + mi * 16 + lq * 4 + r;
        int col = ccol0 + ni * 16 + lr;
        float v = acc[mi][ni][r];
        if (EPI == 3) {
          float pv = __shfl_xor(v, 1);
          if ((lr & 1) == 0) {
            float res = v / (1.f + __expf(-v)) * pv;
            ((unsigned short*)Cout)[(u64)row * (N >> 1) + (col >> 1)] = f2bf(res);
          }
        } else {
          ((unsigned short*)Cout)[(u64)row * N + col] = f2bf(v);
        }
      }
}

// ---------------- RoPE + head split + V transpose ----------------
__global__ __launch_bounds__(256) void k_rope_heads(const unsigned short* __restrict__ qkv,
                                                    const float* __restrict__ cosT,
                                                    const float* __restrict__ sinT,
                                                    unsigned short* __restrict__ q_r,
                                                    unsigned short* __restrict__ k_r,
                                                    unsigned short* __restrict__ v_t) {
  int st = blockIdx.x, hh = blockIdx.y, b = blockIdx.z;
  int t = threadIdx.x;
  int r = t >> 2, cg = (t & 3) * 16;
  int s = st * 64 + r;
  u64 rowb = ((u64)(b * Ssz + s)) * (3 * Dsz);
  u64 bh = (u64)(b * Hn + hh);
  const unsigned int* qp = (const unsigned int*)(qkv + rowb + hh * 64 + cg);
  const unsigned int* kp = (const unsigned int*)(qkv + rowb + Dsz + hh * 64 + cg);
  const unsigned short* vp = qkv + rowb + 2 * Dsz + hh * 64 + cg;
  uint4 qv0 = *(const uint4*)qp, qv1 = *(const uint4*)(qp + 4);
  uint4 kv0 = *(const uint4*)kp, kv1 = *(const uint4*)(kp + 4);
  int i0 = s * 32 + (cg >> 1);
  float4 cA0 = *(const float4*)&cosT[i0], cA1 = *(const float4*)&cosT[i0 + 4];
  float4 sA0 = *(const float4*)&sinT[i0], sA1 = *(const float4*)&sinT[i0 + 4];
  unsigned int qw[8] = {qv0.x, qv0.y, qv0.z, qv0.w, qv1.x, qv1.y, qv1.z, qv1.w};
  unsigned int kw[8] = {kv0.x, kv0.y, kv0.z, kv0.w, kv1.x, kv1.y, kv1.z, kv1.w};
  float cA[8] = {cA0.x, cA0.y, cA0.z, cA0.w, cA1.x, cA1.y, cA1.z, cA1.w};
  float sA[8] = {sA0.x, sA0.y, sA0.z, sA0.w, sA1.x, sA1.y, sA1.z, sA1.w};
  unsigned int oq[8], ok[8];
#pragma unroll
  for (int j = 0; j < 8; ++j) {
    float c = cA[j], sn = sA[j];
    float qe = bf2f((unsigned short)(qw[j] & 0xffff)), qo = bf2f((unsigned short)(qw[j] >> 16));
    float ke = bf2f((unsigned short)(kw[j] & 0xffff)), ko = bf2f((unsigned short)(kw[j] >> 16));
    oq[j] = (unsigned int)f2bf(qe * c - qo * sn) | ((unsigned int)f2bf(qo * c + qe * sn) << 16);
    ok[j] = (unsigned int)f2bf(ke * c - ko * sn) | ((unsigned int)f2bf(ko * c + ke * sn) << 16);
  }
  u64 dst = (bh * Ssz + s) * 64 + cg;
  uint4 a0; a0.x = oq[0]; a0.y = oq[1]; a0.z = oq[2]; a0.w = oq[3];
  uint4 a1; a1.x = oq[4]; a1.y = oq[5]; a1.z = oq[6]; a1.w = oq[7];
  ((uint4*)&q_r[dst])[0] = a0; ((uint4*)&q_r[dst])[1] = a1;
  uint4 b0; b0.x = ok[0]; b0.y = ok[1]; b0.z = ok[2]; b0.w = ok[3];
  uint4 b1; b1.x = ok[4]; b1.y = ok[5]; b1.z = ok[6]; b1.w = ok[7];
  ((uint4*)&k_r[dst])[0] = b0; ((uint4*)&k_r[dst])[1] = b1;
  __shared__ unsigned short vt_lds[64][65];
  uint4 vv0 = *(const uint4*)vp, vv1 = *(const uint4*)(vp + 8);
  unsigned int vw[8] = {vv0.x, vv0.y, vv0.z, vv0.w, vv1.x, vv1.y, vv1.z, vv1.w};
#pragma unroll
  for (int j = 0; j < 8; ++j) {
    vt_lds[r][cg + 2 * j] = (unsigned short)(vw[j] & 0xffff);
    vt_lds[r][cg + 2 * j + 1] = (unsigned short)(vw[j] >> 16);
  }
  __syncthreads();
  unsigned int ov[8];
#pragma unroll
  for (int j = 0; j < 8; ++j) {
    unsigned short lo = vt_lds[cg + 2 * j][r], hi = vt_lds[cg + 2 * j + 1][r];
    ov[j] = (unsigned int)lo | ((unsigned int)hi << 16);
  }
  u64 vdst = bh * ((u64)DHn * Ssz) + (u64)r * Ssz + st * 64 + cg;
  uint4 c0v; c0v.x = ov[0]; c0v.y = ov[1]; c0v.z = ov[2]; c0v.w = ov[3];
  uint4 c1v; c1v.x = ov[4]; c1v.y = ov[5]; c1v.z = ov[6]; c1v.w = ov[7];
  ((uint4*)&v_t[vdst])[0] = c0v; ((uint4*)&v_t[vdst])[1] = c1v;
}

// ---------------- fused attention (LDS-staged K/V, swapped QK^T) ----------------
__global__ __launch_bounds__(256) void k_attn(const unsigned short* __restrict__ qr,
                                              const unsigned short* __restrict__ kr,
                                              const unsigned short* __restrict__ vt,
                                              unsigned short* __restrict__ outp) {
  __shared__ unsigned short Klds[2][2][64 * 32] __attribute__((aligned(16)));
  __shared__ unsigned short Vlds[2][2][64 * 32] __attribute__((aligned(16)));
  __shared__ unsigned short Plds[4][16 * 64] __attribute__((aligned(16)));
  int qt = blockIdx.x, hh = blockIdx.y, b = blockIdx.z;
  int t = threadIdx.x, w = t >> 6, l = t & 63;
  int lr = l & 15, lq = l >> 4;
  u64 bh = (u64)(b * Hn + hh);
  const unsigned short* Qp = qr + bh * (Ssz * DHn);
  const unsigned short* Kp = kr + bh * (Ssz * DHn);
  const unsigned short* Vp = vt + bh * ((u64)DHn * Ssz);
  int q0 = qt * 64 + w * 16;
  bf16x8 qlo = *(const bf16x8*)&Qp[(q0 + lr) * DHn + lq * 8];
  bf16x8 qhi = *(const bf16x8*)&Qp[(q0 + lr) * DHn + 32 + lq * 8];
  int srow = t >> 2;
  int scol8 = (t & 3) * 8;
#define STAGEKV(bufi, kbase)                                                         \
  do {                                                                               \
    gload_lds16(&Kp[((kbase) + srow) * 64 + scol8],      (char*)&Klds[bufi][0][0] + t * 16); \
    gload_lds16(&Kp[((kbase) + srow) * 64 + 32 + scol8], (char*)&Klds[bufi][1][0] + t * 16); \
    gload_lds16(&Vp[(u64)srow * Ssz + (kbase) + scol8],      (char*)&Vlds[bufi][0][0] + t * 16); \
    gload_lds16(&Vp[(u64)srow * Ssz + (kbase) + 32 + scol8], (char*)&Vlds[bufi][1][0] + t * 16); \
  } while (0)
  float m_col = -1e30f, lsum = 0.f;
  float m_row[4] = {-1e30f, -1e30f, -1e30f, -1e30f};
  f32x4 o[4];
#pragma unroll
  for (int r = 0; r < 4; ++r) o[r] = (f32x4){0.f, 0.f, 0.f, 0.f};
  char* Pw = (char*)&Plds[w][0];

  STAGEKV(0, 0);
  asm volatile("s_waitcnt vmcnt(0)" ::: "memory");
  __syncthreads();
  int buf = 0;
  for (int kb = 0; kb < Ssz; kb += 64) {
    if (kb + 64 < Ssz) STAGEKV(buf ^ 1, kb + 64);
    float p[4][4];
#pragma unroll
    for (int ct = 0; ct < 4; ++ct) {
      bf16x8 klo = *(const bf16x8*)&Klds[buf][0][(ct * 16 + lr) * 32 + lq * 8];
      bf16x8 khi = *(const bf16x8*)&Klds[buf][1][(ct * 16 + lr) * 32 + lq * 8];
      f32x4 z = (f32x4){0.f, 0.f, 0.f, 0.f};
      f32x4 slo = __builtin_amdgcn_mfma_f32_16x16x32_bf16(klo, qlo, z, 0, 0, 0);
      f32x4 shi = __builtin_amdgcn_mfma_f32_16x16x32_bf16(khi, qhi, z, 0, 0, 0);
      int kg0 = kb + ct * 16 + lq * 4;
      int qg = q0 + lr;
#pragma unroll
      for (int r = 0; r < 4; ++r) p[ct][r] = (kg0 + r <= qg ? shi[r] : slo[r]) * SCALE_;
    }
    float tm = p[0][0];
#pragma unroll
    for (int ct = 0; ct < 4; ++ct)
#pragma unroll
      for (int r = 0; r < 4; ++r) tm = fmaxf(tm, p[ct][r]);
    tm = fmaxf(tm, __shfl_xor(tm, 16));
    tm = fmaxf(tm, __shfl_xor(tm, 32));
    float m_new = fmaxf(m_col, tm);
    lsum *= __expf(m_col - m_new);
    m_col = m_new;
#pragma unroll
    for (int r = 0; r < 4; ++r) {
      float mr = __shfl(m_col, lq * 4 + r);
      float scf = __expf(m_row[r] - mr);
      m_row[r] = mr;
      o[0][r] *= scf; o[1][r] *= scf; o[2][r] *= scf; o[3][r] *= scf;
    }
#pragma unroll
    for (int ct = 0; ct < 4; ++ct) {
      float e0 = __expf(p[ct][0] - m_col);
      float e1 = __expf(p[ct][1] - m_col);
      float e2 = __expf(p[ct][2] - m_col);
      float e3 = __expf(p[ct][3] - m_col);
      lsum += e0 + e1 + e2 + e3;
      ushort4 pk; pk.x = f2bf(e0); pk.y = f2bf(e1); pk.z = f2bf(e2); pk.w = f2bf(e3);
      int byte_ = (lr * 128 + ct * 32 + lq * 8) ^ ((lr & 7) << 4);
      *(ushort4*)(Pw + byte_) = pk;
    }
    asm volatile("s_waitcnt lgkmcnt(0)" ::: "memory");
    __builtin_amdgcn_sched_barrier(0);
#pragma unroll
    for (int ks = 0; ks < 2; ++ks) {
      int pb = (lr * 128 + ks * 64 + lq * 16) ^ ((lr & 7) << 4);
      bf16x8 pa = *(const bf16x8*)(Pw + pb);
#pragma unroll
      for (int nt = 0; nt < 4; ++nt) {
        bf16x8 vb = *(const bf16x8*)&Vlds[buf][ks][(nt * 16 + lr) * 32 + lq * 8];
        o[nt] = __builtin_amdgcn_mfma_f32_16x16x32_bf16(pa, vb, o[nt], 0, 0, 0);
      }
    }
    asm volatile("s_waitcnt vmcnt(0)" ::: "memory");
    __syncthreads();
    buf ^= 1;
  }
  lsum += __shfl_xor(lsum, 16);
  lsum += __shfl_xor(lsum, 32);
  u64 obase = ((u64)b * Ssz) * Dsz + (u64)hh * DHn;
#pragma unroll
  for (int r = 0; r < 4; ++r) {
    float ls = __shfl(lsum, lq * 4 + r);
    float inv = 1.f / ls;
    int qrow = q0 + lq * 4 + r;
#pragma unroll
    for (int nt = 0; nt < 4; ++nt)
      outp[obase + (u64)qrow * Dsz + nt * 16 + lr] = f2bf(o[nt][r] * inv);
  }
#undef STAGEKV
}

// ---------------- scores = hf @ w_score ----------------
__global__ __launch_bounds__(256) void k_scores(const float* __restrict__ hf,
                                                const float* __restrict__ wsc,
                                                float* __restrict__ scores) {
  int row = blockIdx.x * 4 + (threadIdx.x >> 6);
  int l = threadIdx.x & 63;
  const float* xr = hf + (u64)row * Dsz;
  float acc = 0.f;
#pragma unroll
  for (int j = 0; j < 4; ++j) {
    float4 v = *(const float4*)&xr[(j * 64 + l) * 4];
    float4 ww = *(const float4*)&wsc[(j * 64 + l) * 4];
    acc += v.x * ww.x + v.y * ww.y + v.z * ww.z + v.w * ww.w;
  }
#pragma unroll
  for (int m = 1; m < 64; m <<= 1) acc += __shfl_xor(acc, m);
  if (l == 0) scores[row] = acc;
}

// ---------------- softmax over S (per batch) ----------------
__global__ __launch_bounds__(256) void k_softmax_s(const float* __restrict__ sc,
                                                   float* __restrict__ pw) {
  int b = blockIdx.x, t = threadIdx.x;
  const float* sr = sc + b * Ssz;
  float4 v = *(const float4*)&sr[t * 4];
  float mx = fmaxf(fmaxf(v.x, v.y), fmaxf(v.z, v.w));
#pragma unroll
  for (int m = 1; m < 64; m <<= 1) mx = fmaxf(mx, __shfl_xor(mx, m));
  __shared__ float red[4];
  if ((t & 63) == 0) red[t >> 6] = mx;
  __syncthreads();
  mx = fmaxf(fmaxf(red[0], red[1]), fmaxf(red[2], red[3]));
  float e0 = __expf(v.x - mx), e1 = __expf(v.y - mx), e2 = __expf(v.z - mx), e3 = __expf(v.w - mx);
  float sm = e0 + e1 + e2 + e3;
#pragma unroll
  for (int m = 1; m < 64; m <<= 1) sm += __shfl_xor(sm, m);
  __shared__ float red2[4];
  if ((t & 63) == 0) red2[t >> 6] = sm;
  __syncthreads();
  sm = red2[0] + red2[1] + red2[2] + red2[3];
  float inv = 1.f / sm;
  float4 o; o.x = e0 * inv; o.y = e1 * inv; o.z = e2 * inv; o.w = e3 * inv;
  *(float4*)&pw[b * Ssz + t * 4] = o;
}

// ---------------- pooled[b][d] = sum_s pw[b][s]*hf[b][s][d] ----------------
__global__ __launch_bounds__(256) void k_pool(const float* __restrict__ hf,
                                              const float* __restrict__ pw,
                                              float* __restrict__ pooled) {
  int b = blockIdx.y;
  int d = blockIdx.x * 256 + threadIdx.x;
  const float* pwb = pw + b * Ssz;
  float acc = 0.f;
  for (int s = 0; s < Ssz; ++s) acc += pwb[s] * hf[((u64)(b * Ssz + s)) * Dsz + d];
  pooled[b * Dsz + d] = acc;
}

// ---------------- out[b][n] = sum_k pooled[b][k]*wcls[k][n] ----------------
__global__ __launch_bounds__(256) void k_cls(const float* __restrict__ pooled,
                                             const float* __restrict__ wcls,
                                             float* __restrict__ outp) {
  int n = blockIdx.x * 64 + (threadIdx.x & 63);
  int b = threadIdx.x >> 6;
  const float* pb = pooled + b * Dsz;
  float acc = 0.f;
  for (int k = 0; k < Dsz; ++k) acc += pb[k] * wcls[(u64)k * Ssz + n];
  outp[b * Ssz + n] = acc;
}

extern "C" void kernel_launch(void* const* d_in, const int* in_sizes, int n_in,
                              void* d_out, int out_size, void* d_ws, size_t ws_size,
                              hipStream_t stream) {
  (void)in_sizes; (void)n_in; (void)out_size; (void)ws_size;
  const int*   tokens  = (const int*)  d_in[0];
  const float* tok_emb = (const float*)d_in[1];
  const float* ln1_s   = (const float*)d_in[2];
  const float* ln1_b   = (const float*)d_in[3];
  const float* w_qkv   = (const float*)d_in[4];
  const float* w_proj  = (const float*)d_in[5];
  const float* ln2_s   = (const float*)d_in[6];
  const float* ln2_b   = (const float*)d_in[7];
  const float* w_in    = (const float*)d_in[8];
  const float* w_out   = (const float*)d_in[9];
  const float* lnf_s   = (const float*)d_in[10];
  const float* lnf_b   = (const float*)d_in[11];
  const float* w_score = (const float*)d_in[12];
  const float* w_cls   = (const float*)d_in[13];
  float* outp = (float*)d_out;
  char* ws = (char*)d_ws;

  unsigned short* qkv    = (unsigned short*)(ws + 0);
  unsigned short* q_r    = (unsigned short*)(ws + 25165824ull);
  unsigned short* k_r    = (unsigned short*)(ws + 33554432ull);
  unsigned short* v_t    = (unsigned short*)(ws + 41943040ull);
  unsigned short* a_out  = (unsigned short*)(ws + 50331648ull);
  float*          hf     = (float*)(ws + 0);
  unsigned short* x_ln   = (unsigned short*)(ws + 67108864ull);
  unsigned short* mbuf   = (unsigned short*)(ws + 75497472ull);
  float*          h      = (float*)(ws + 109051904ull);
  unsigned short* wqkv_t = (unsigned short*)(ws + 125829120ull);
  unsigned short* wproj_t= (unsigned short*)(ws + 132120576ull);
  unsigned short* win_t  = (unsigned short*)(ws + 134217728ull);
  unsigned short* wout_t = (unsigned short*)(ws + 150994944ull);
  float* cosT    = (float*)(ws + 159383552ull);
  float* sinT    = (float*)(ws + 159514624ull);
  float* scoresb = (float*)(ws + 159645696ull);
  float* pwb     = (float*)(ws + 159662080ull);
  float* pooledb = (float*)(ws + 159678464ull);

  dim3 blk(256);
  k_cossin<<<dim3(128), blk, 0, stream>>>(cosT, sinT);
  k_embed<<<dim3(4096), blk, 0, stream>>>(tokens, tok_emb, h);

  for (int l = 0; l < Ln; ++l) {
    k_layernorm<1><<<dim3(4096), blk, 0, stream>>>(h, ln1_s + l * Dsz, ln1_b + l * Dsz, (void*)x_ln);
    k_wt<<<dim3(96, 32), blk, 0, stream>>>(w_qkv + (u64)l * Dsz * 3 * Dsz, wqkv_t, Dsz, 3 * Dsz);
    k_ring128<1><<<dim3(24, 32), blk, 0, stream>>>(x_ln, wqkv_t, nullptr, (void*)qkv, 4096, 3072, 1024);
    k_rope_heads<<<dim3(16, 16, 4), blk, 0, stream>>>(qkv, cosT, sinT, q_r, k_r, v_t);
    k_attn<<<dim3(16, 16, 4), blk, 0, stream>>>(q_r, k_r, v_t, a_out);
    k_wt<<<dim3(32, 32), blk, 0, stream>>>(w_proj + (u64)l * Dsz * Dsz, wproj_t, Dsz, Dsz);
    k_ring128<2><<<dim3(8, 32), blk, 0, stream>>>(a_out, wproj_t, h, (void*)h, 4096, 1024, 1024);
    k_layernorm<1><<<dim3(4096), blk, 0, stream>>>(h, ln2_s + l * Dsz, ln2_b + l * Dsz, (void*)x_ln);
    k_wt_pair<<<dim3(256, 32), blk, 0, stream>>>(w_in + (u64)l * Dsz * 2 * Fsz, win_t);
    k_gemm256<3><<<dim3(512), dim3(512), 0, stream>>>(x_ln, win_t, (void*)mbuf, 4096, 8192, 1024, 32);
    k_wt<<<dim3(32, 128), blk, 0, stream>>>(w_out + (u64)l * Fsz * Dsz, wout_t, Fsz, Dsz);
    k_ring128<2><<<dim3(8, 32), blk, 0, stream>>>(mbuf, wout_t, h, (void*)h, 4096, 1024, 4096);
  }

  k_layernorm<0><<<dim3(4096), blk, 0, stream>>>(h, lnf_s, lnf_b, (void*)hf);
  k_scores<<<dim3(1024), blk, 0, stream>>>(hf, w_score, scoresb);
  k_softmax_s<<<dim3(4), blk, 0, stream>>>(scoresb, pwb);
  k_pool<<<dim3(4, 4), blk, 0, stream>>>(hf, pwb, pooledb);
  k_cls<<<dim3(16), blk, 0, stream>>>(pooledb, w_cls, outp);
}